// Round 4
// baseline (986.778 us; speedup 1.0000x reference)
//
#include <hip/hip_runtime.h>
#include <cstdint>
#include <cstddef>

#define NPTS  32768
#define NB    8
#define RR    32
#define RR3   32768
#define NVOX  (NB*RR3)          // 262144

typedef __bf16 bf16_t;
typedef __bf16 bf16x8 __attribute__((ext_vector_type(8)));
typedef __bf16 bf16x4 __attribute__((ext_vector_type(4)));
typedef float  f32x4  __attribute__((ext_vector_type(4)));

// adaptive load: input tensors may be fp32 or bf16 (detected at runtime)
__device__ __forceinline__ float LD(const void* p, size_t i, int isf){
  return isf ? ((const float*)p)[i] : (float)((const bf16_t*)p)[i];
}

// ---------------------------------------------------------------- reductions
__device__ __forceinline__ float wave_sum(float v){
#pragma unroll
  for (int o = 32; o > 0; o >>= 1) v += __shfl_down(v, o, 64);
  return v;
}
__device__ __forceinline__ float wave_max(float v){
#pragma unroll
  for (int o = 32; o > 0; o >>= 1) v = fmaxf(v, __shfl_down(v, o, 64));
  return v;
}

// --------------------------------------------------------------- dtype detect (parallel)
__global__ __launch_bounds__(256) void detect_kernel(const void* __restrict__ coords,
                                                     int* __restrict__ flag){
  int i = blockIdx.x*256 + threadIdx.x;
  const uint16_t* p = (const uint16_t*)coords;
  if ((p[i] & 0x7F80) == 0x7F80) atomicOr(flag, 1);   // 1 = fp32
}

// --------------------------------------------------------------- stats (3-phase parallel)
__global__ __launch_bounds__(256) void stats_sum_kernel(
    const void* __restrict__ coords, const int* __restrict__ flag, float* __restrict__ ssum){
  __shared__ float l[12];
  int isf = *flag;
  int b = blockIdx.x >> 5, blk = blockIdx.x & 31;     // 32 blocks per batch
  int t = threadIdx.x;
  size_t cb = ((size_t)b * 3) << 15;
  float sx = 0.f, sy = 0.f, sz = 0.f;
  int n0 = blk << 10;
  for (int n = n0 + t; n < n0 + 1024; n += 256){
    sx += LD(coords, cb + n, isf);
    sy += LD(coords, cb + NPTS + n, isf);
    sz += LD(coords, cb + 2*NPTS + n, isf);
  }
  sx = wave_sum(sx); sy = wave_sum(sy); sz = wave_sum(sz);
  int w = t >> 6;
  if ((t & 63) == 0){ l[w] = sx; l[4+w] = sy; l[8+w] = sz; }
  __syncthreads();
  if (t == 0){
    unsafeAtomicAdd(&ssum[b*4+0], l[0]+l[1]+l[2]+l[3]);
    unsafeAtomicAdd(&ssum[b*4+1], l[4]+l[5]+l[6]+l[7]);
    unsafeAtomicAdd(&ssum[b*4+2], l[8]+l[9]+l[10]+l[11]);
  }
}

__global__ __launch_bounds__(256) void stats_max_kernel(
    const void* __restrict__ coords, const int* __restrict__ flag,
    const float* __restrict__ ssum, unsigned* __restrict__ smax){
  __shared__ float l[4];
  int isf = *flag;
  int b = blockIdx.x >> 5, blk = blockIdx.x & 31;
  int t = threadIdx.x;
  size_t cb = ((size_t)b * 3) << 15;
  float mx = ssum[b*4+0] * (1.f/NPTS);
  float my = ssum[b*4+1] * (1.f/NPTS);
  float mz = ssum[b*4+2] * (1.f/NPTS);
  float mm = 0.f;
  int n0 = blk << 10;
  for (int n = n0 + t; n < n0 + 1024; n += 256){
    float cx = LD(coords, cb + n, isf) - mx;
    float cy = LD(coords, cb + NPTS + n, isf) - my;
    float cz = LD(coords, cb + 2*NPTS + n, isf) - mz;
    mm = fmaxf(mm, cx*cx + cy*cy + cz*cz);
  }
  mm = wave_max(mm);
  int w = t >> 6;
  if ((t & 63) == 0) l[w] = mm;
  __syncthreads();
  if (t == 0){
    float m = fmaxf(fmaxf(l[0], l[1]), fmaxf(l[2], l[3]));
    atomicMax(&smax[b], __float_as_uint(m));          // valid: m >= 0
  }
}

__global__ void stats_fin_kernel(const float* __restrict__ ssum,
                                 const unsigned* __restrict__ smax,
                                 float* __restrict__ stats){
  int b = threadIdx.x;
  if (b >= NB) return;
  float m = __uint_as_float(smax[b]);
  float inv = 32.f / (2.f * sqrtf(m) * (1.f + 1e-6f));
  float4 o;
  o.x = ssum[b*4+0] * (1.f/NPTS);
  o.y = ssum[b*4+1] * (1.f/NPTS);
  o.z = ssum[b*4+2] * (1.f/NPTS);
  o.w = inv;
  ((float4*)stats)[b] = o;
}

// --------------------------------------------------------------- corners
__device__ __forceinline__ void compute_corners(const void* __restrict__ coords, float4 st,
                                                int b, int n, int isf, int* idx, float* wts){
  size_t cbase = ((size_t)b * 3) << 15;
  float cx = LD(coords, cbase + n, isf)          - st.x;
  float cy = LD(coords, cbase + NPTS + n, isf)   - st.y;
  float cz = LD(coords, cbase + 2*NPTS + n, isf) - st.z;
  float vx = fminf(fmaxf(cx*st.w + 16.f, 0.f), 31.f);
  float vy = fminf(fmaxf(cy*st.w + 16.f, 0.f), 31.f);
  float vz = fminf(fmaxf(cz*st.w + 16.f, 0.f), 31.f);
  int lx = (int)vx, ly = (int)vy, lz = (int)vz;
  float fx = vx - (float)lx, fy = vy - (float)ly, fz = vz - (float)lz;
#pragma unroll
  for (int k = 0; k < 8; ++k){
    int dx = k >> 2, dy = (k >> 1) & 1, dz = k & 1;
    int xi = min(lx+dx, 31), yi = min(ly+dy, 31), zi = min(lz+dz, 31);
    idx[k] = (xi << 10) + (yi << 5) + zi;
    wts[k] = (dx ? fx : 1.f-fx) * (dy ? fy : 1.f-fy) * (dz ? fz : 1.f-fz);
  }
}

// --------------------------------------------------------------- transpose feat -> [B*N,64] bf16
__global__ __launch_bounds__(256) void transpose_kernel(
    const void* __restrict__ feat, const int* __restrict__ flag, bf16_t* __restrict__ feat_t)
{
  __shared__ float tile[64][65];
  int isf = *flag;
  int blk = blockIdx.x;            // 4096 = B * (N/64)
  int b = blk >> 9;
  int n0 = (blk & 511) << 6;
  int t = threadIdx.x, lane = t & 63, w = t >> 6;
  size_t base = ((size_t)b << 21); // b*64*N
  for (int ci = w; ci < 64; ci += 4)
    tile[ci][lane] = LD(feat, base + ((size_t)ci << 15) + n0 + lane, isf);
  __syncthreads();
  for (int i = t; i < 512; i += 256){
    int p = i >> 3, seg = i & 7;
    bf16x8 o;
#pragma unroll
    for (int e = 0; e < 8; ++e) o[e] = (bf16_t)tile[seg*8+e][p];
    *(bf16x8*)(feat_t + (((size_t)(b*NPTS + n0 + p)) << 6) + seg*8) = o;
  }
}

// --------------------------------------------------------------- voxelize: hist / offsets / fill / gather
__global__ __launch_bounds__(256) void hist_kernel(
    const void* __restrict__ coords, const float* __restrict__ stats,
    const int* __restrict__ flag, unsigned* __restrict__ hist)
{
  int isf = *flag;
  int gid = blockIdx.x*256 + threadIdx.x;
  int b = gid >> 15, n = gid & (NPTS-1);
  float4 st = ((const float4*)stats)[b];
  int idx[8]; float wts[8];
  compute_corners(coords, st, b, n, isf, idx, wts);
#pragma unroll
  for (int k = 0; k < 8; ++k) atomicAdd(&hist[(b << 15) + idx[k]], 1u);
}

__global__ __launch_bounds__(256) void offsets_kernel(
    const unsigned* __restrict__ hist, unsigned* __restrict__ offsets,
    unsigned* __restrict__ counter)
{
  int v = blockIdx.x*256 + threadIdx.x;
  int lane = threadIdx.x & 63;
  unsigned h = hist[v];
  unsigned pre = h;
#pragma unroll
  for (int o = 1; o < 64; o <<= 1){
    unsigned x = __shfl_up(pre, o, 64);
    if (lane >= o) pre += x;
  }
  unsigned total = __shfl(pre, 63, 64);
  unsigned base = 0;
  if (lane == 63) base = atomicAdd(counter, total);
  base = __shfl(base, 63, 64);
  offsets[v] = base + pre - h;      // exclusive start of segment v
}

__global__ __launch_bounds__(256) void fill_kernel(
    const void* __restrict__ coords, const float* __restrict__ stats,
    const int* __restrict__ flag, unsigned* __restrict__ offsets,
    uint2* __restrict__ sorted)
{
  int isf = *flag;
  int gid = blockIdx.x*256 + threadIdx.x;
  int b = gid >> 15, n = gid & (NPTS-1);
  float4 st = ((const float4*)stats)[b];
  int idx[8]; float wts[8];
  compute_corners(coords, st, b, n, isf, idx, wts);
#pragma unroll
  for (int k = 0; k < 8; ++k){
    unsigned pos = atomicAdd(&offsets[(b << 15) + idx[k]], 1u);   // bumps to segment end
    sorted[pos] = make_uint2((unsigned)n, __float_as_uint(wts[k]));
  }
}

// PERSISTENT gather: 2048 blocks x 4 waves = 8192 waves (exactly 8/SIMD device-
// wide); each wave grid-strides over 32 voxels so waves stay resident for the
// whole kernel (the previous 65536-tiny-block version averaged only ~11/32
// waves/CU -- CP refill couldn't keep up with ~1us block lifetimes).
// Per voxel: lane = g*8 + c8 (8 entry slots x 8 channels of 16B).
// cnt==0 fast path; unpredicated 64-entry blocks for dense voxels; predicated
// 16-entry depth-2 tail for the typical cnt~8 voxel (cuts padded-FMA waste 4x).
__global__ __launch_bounds__(256) void gather_kernel(
    const uint2* __restrict__ sorted, const unsigned* __restrict__ offsets_end,
    const unsigned* __restrict__ hist, const bf16_t* __restrict__ feat_t,
    bf16_t* __restrict__ vox)
{
  const int NW = 2048*4;               // total waves in grid
  int wid = blockIdx.x*4 + (threadIdx.x >> 6);
  int lane = threadIdx.x & 63;
  int g  = lane >> 3;                  // entry slot group
  int c8 = lane & 7;                   // 8 bf16 channels (16B) per lane

  for (int v = wid; v < NVOX; v += NW){
    unsigned end = offsets_end[v];
    unsigned cnt = hist[v];
    if (cnt == 0){
      if (g == 0){
        bf16x8 z;
#pragma unroll
        for (int j = 0; j < 8; ++j) z[j] = (bf16_t)0.f;
        *(bf16x8*)(vox + ((size_t)v << 6) + c8*8) = z;
      }
      continue;
    }
    int b = v >> 15;
    size_t fbase = ((size_t)b << 21);  // b*NPTS*64
    unsigned base = end - cnt;
    float acc[8] = {0.f,0.f,0.f,0.f,0.f,0.f,0.f,0.f};
    float cw = 0.f;
    // ---- full 64-entry blocks (unpredicated) ----
    for (; base + 64 <= end; base += 64){
      uint2 e[8];
#pragma unroll
      for (int d = 0; d < 8; ++d) e[d] = sorted[base + g + 8*d];
      bf16x8 f[8];
#pragma unroll
      for (int d = 0; d < 8; ++d)
        f[d] = *(const bf16x8*)(feat_t + fbase + ((size_t)e[d].x << 6) + c8*8);
#pragma unroll
      for (int d = 0; d < 8; ++d){
        float w = __uint_as_float(e[d].y);
#pragma unroll
        for (int j = 0; j < 8; ++j) acc[j] += w * (float)f[d][j];
        cw += w;
      }
    }
    // ---- 16-entry tail (predicated, depth 2) ----
    for (; base < end; base += 16){
      unsigned i0 = base + g, i1 = base + g + 8;
      uint2 e0 = (i0 < end) ? sorted[i0] : make_uint2(0u, 0u);
      uint2 e1 = (i1 < end) ? sorted[i1] : make_uint2(0u, 0u);
      bf16x8 f0 = *(const bf16x8*)(feat_t + fbase + ((size_t)e0.x << 6) + c8*8);
      bf16x8 f1 = *(const bf16x8*)(feat_t + fbase + ((size_t)e1.x << 6) + c8*8);
      float w0 = __uint_as_float(e0.y), w1 = __uint_as_float(e1.y);
#pragma unroll
      for (int j = 0; j < 8; ++j) acc[j] += w0 * (float)f0[j] + w1 * (float)f1[j];
      cw += w0 + w1;
    }
    // combine the 8 entry-slot groups (lanes differing in bits 3,4,5)
#pragma unroll
    for (int m = 8; m < 64; m <<= 1){
#pragma unroll
      for (int j = 0; j < 8; ++j) acc[j] += __shfl_xor(acc[j], m, 64);
      cw += __shfl_xor(cw, m, 64);
    }
    if (g == 0){
      float inv = 1.f / fmaxf(cw, 1e-8f);
      bf16x8 o;
#pragma unroll
      for (int j = 0; j < 8; ++j) o[j] = (bf16_t)(acc[j]*inv);
      *(bf16x8*)(vox + ((size_t)v << 6) + c8*8) = o;
    }
  }
}

// --------------------------------------------------------------- conv3d 3x3x3 + BN + LeakyReLU
// channels-last in/out [B*R3, 64]; tile: x fixed, y0..y0+3, z0..z0+15 (64 voxels / wg).
// Weights are consumed as per-wave REGISTER fragments loaded straight from a
// fragment-major pack [27][ks=2][j=4][lane=64] (16B/lane, coalesced, L2-hot),
// 3-buffer rotation prefetching 2 taps ahead -> ZERO barriers in the tap loop.
// Input tile: true 128B rows, T2-style XOR swizzle (chunk ^= row&7) on both the
// staging write and the fragment read -> conflict-free ds_read_b128.
struct W8 { bf16x8 v[8]; };

__device__ __forceinline__ void load_wfrag(const bf16_t* __restrict__ wpack, int tap, int lane, W8& w){
#pragma unroll
  for (int f = 0; f < 8; ++f)
    w.v[f] = *(const bf16x8*)(wpack + (size_t)(tap*8 + f)*512 + lane*8);
}

__device__ __forceinline__ void tap_mfma(const bf16_t* lds_in, int rowidx, int quad, const W8& w,
                                         f32x4& a0, f32x4& a1, f32x4& a2, f32x4& a3){
  int swz = rowidx & 7;
#pragma unroll
  for (int ks = 0; ks < 2; ++ks){
    bf16x8 a = *(const bf16x8*)(lds_in + rowidx*64 + ((((ks<<2)|quad) ^ swz) << 3));
    a0 = __builtin_amdgcn_mfma_f32_16x16x32_bf16(a, w.v[ks*4+0], a0, 0, 0, 0);
    a1 = __builtin_amdgcn_mfma_f32_16x16x32_bf16(a, w.v[ks*4+1], a1, 0, 0, 0);
    a2 = __builtin_amdgcn_mfma_f32_16x16x32_bf16(a, w.v[ks*4+2], a2, 0, 0, 0);
    a3 = __builtin_amdgcn_mfma_f32_16x16x32_bf16(a, w.v[ks*4+3], a3, 0, 0, 0);
  }
}

__global__ __launch_bounds__(256, 3) void conv3d_kernel(
    const bf16_t* __restrict__ in, const bf16_t* __restrict__ wpack,   // frag-major [27][2][4][64][8]
    const float* __restrict__ scale, const float* __restrict__ shift,
    bf16_t* __restrict__ out)
{
  __shared__ bf16_t lds_in[324*64];      // 41,472 B, XOR-swizzled 128B rows
  int bid = blockIdx.x;
  int b  = bid >> 9;
  int x  = (bid >> 4) & 31;
  int y0 = ((bid >> 1) & 7) << 2;
  int z0 = (bid & 1) << 4;
  int t = threadIdx.x;
  for (int seg = t; seg < 324*8; seg += 256){
    int row = seg >> 3, part = seg & 7;
    int hx = row / 108, rem = row - hx*108;
    int hy = rem / 18,  hz = rem - hy*18;
    int gx = x + hx - 1, gy = y0 + hy - 1, gz = z0 + hz - 1;
    uint4 val = make_uint4(0u,0u,0u,0u);
    if ((unsigned)gx < 32u && (unsigned)gy < 32u && (unsigned)gz < 32u)
      val = *(const uint4*)(in + ((((size_t)(b*RR3 + ((gx<<10)+(gy<<5)+gz))) << 6) + part*8));
    *(uint4*)(lds_in + row*64 + ((part ^ (row & 7)) << 3)) = val;
  }
  int wave = t >> 6, lane = t & 63;
  int lrow = lane & 15, quad = lane >> 4;
  int rowbase = wave*18 + lrow;          // + dx*108 + dy*18 + dz per tap
  f32x4 acc0 = 0.f, acc1 = 0.f, acc2 = 0.f, acc3 = 0.f;

  W8 wA, wB, wC;
  load_wfrag(wpack, 0, lane, wA);        // prefetch tap 0
  load_wfrag(wpack, 1, lane, wB);        // prefetch tap 1
  __syncthreads();                       // only barrier: input tile ready

#pragma unroll
  for (int p = 0; p < 9; ++p){
    int t0 = 3*p, t1 = 3*p+1, t2 = 3*p+2;
    int n0 = (t0+2 < 27) ? t0+2 : 26;
    int n1 = (t1+2 < 27) ? t1+2 : 26;
    int n2 = (t2+2 < 27) ? t2+2 : 26;
    load_wfrag(wpack, n0, lane, wC);
    { int dx = t0/9, r9 = t0-dx*9, dy = r9/3, dz = r9-dy*3;
      tap_mfma(lds_in, rowbase + dx*108 + dy*18 + dz, quad, wA, acc0, acc1, acc2, acc3); }
    load_wfrag(wpack, n1, lane, wA);
    { int dx = t1/9, r9 = t1-dx*9, dy = r9/3, dz = r9-dy*3;
      tap_mfma(lds_in, rowbase + dx*108 + dy*18 + dz, quad, wB, acc0, acc1, acc2, acc3); }
    load_wfrag(wpack, n2, lane, wB);
    { int dx = t2/9, r9 = t2-dx*9, dy = r9/3, dz = r9-dy*3;
      tap_mfma(lds_in, rowbase + dx*108 + dy*18 + dz, quad, wC, acc0, acc1, acc2, acc3); }
  }

  f32x4 accs[4] = {acc0, acc1, acc2, acc3};
#pragma unroll
  for (int j = 0; j < 4; ++j){
    int co = j*16 + lrow;
    float sc = scale[co], sh = shift[co];
#pragma unroll
    for (int r = 0; r < 4; ++r){
      int zl = quad*4 + r;
      size_t o = (((size_t)(b*RR3 + ((x<<10) + ((y0+wave)<<5) + z0 + zl))) << 6) + co;
      float val = accs[j][r]*sc + sh;
      val = fmaxf(val, 0.1f*val);                    // LeakyReLU(0.1)
      out[o] = (bf16_t)val;
    }
  }
}

// --------------------------------------------------------------- devoxelize + point branch
__global__ __launch_bounds__(256) void devox_kernel(
    const bf16_t* __restrict__ g,        // conv2 out [B*R3,64] channels-last
    const bf16_t* __restrict__ feat_t,   // [B*N,64] bf16 point-major
    const void* __restrict__ coords,
    const void* __restrict__ mlp_w,      // [64,64]
    const float* __restrict__ stats, const int* __restrict__ flag,
    const float* __restrict__ pscale, const float* __restrict__ pshift,
    void* __restrict__ out)              // [B,64,N]
{
  __shared__ bf16_t lf[32*72];           // feat tile [p][ci]
  __shared__ bf16_t lw[64*64];           // mlp_w [o][c]
  __shared__ float  lo[64*33];           // out tile [co][p]
  int t = threadIdx.x;
  int isf = *flag;
  int pb = blockIdx.x << 5;              // 32 points / block
  int b = pb >> 15, n0 = pb & (NPTS - 1);
  {
    int p = t >> 3, seg = t & 7;         // 256 threads == 32 points x 8 segs
    *(bf16x8*)(lf + p*72 + seg*8) =
        *(const bf16x8*)(feat_t + (((size_t)(b*NPTS + n0 + p)) << 6) + seg*8);
  }
  for (int i = t; i < 4096; i += 256)
    lw[i] = (bf16_t)LD(mlp_w, i, isf);
  __syncthreads();
  int p = t >> 3, gseg = t & 7;
  int n = n0 + p;
  float4 st = ((const float4*)stats)[b];
  int idx[8]; float wts[8];
  compute_corners(coords, st, b, n, isf, idx, wts);
  float dv[8] = {0,0,0,0,0,0,0,0};
#pragma unroll
  for (int k = 0; k < 8; ++k){
    bf16x8 gv = *(const bf16x8*)(g + (((size_t)(b*RR3 + idx[k])) << 6) + gseg*8);
    float w = wts[k];
#pragma unroll
    for (int j = 0; j < 8; ++j) dv[j] += w * (float)gv[j];
  }
  float pv[8] = {0,0,0,0,0,0,0,0};
#pragma unroll
  for (int s = 0; s < 8; ++s){
    bf16x8 fv = *(const bf16x8*)(lf + p*72 + s*8);
    float fvf[8];
#pragma unroll
    for (int e = 0; e < 8; ++e) fvf[e] = (float)fv[e];
#pragma unroll
    for (int j = 0; j < 8; ++j){
      bf16x8 wv = *(const bf16x8*)(lw + (gseg*8 + j)*64 + s*8);
#pragma unroll
      for (int e = 0; e < 8; ++e) pv[j] += (float)wv[e] * fvf[e];
    }
  }
#pragma unroll
  for (int j = 0; j < 8; ++j){
    int co = gseg*8 + j;
    float q = pv[j]*pscale[co] + pshift[co];
    q = fmaxf(q, 0.f);
    lo[co*33 + p] = dv[j] + q;
  }
  __syncthreads();
  size_t obase = ((size_t)b << 21) + n0;
  if (isf){
    float* of = (float*)out;
    for (int i = t; i < 2048; i += 256){
      int co = i >> 5, pp = i & 31;
      of[obase + ((size_t)co << 15) + pp] = lo[co*33 + pp];
    }
  } else {
    bf16_t* oh = (bf16_t*)out;
    for (int i = t; i < 2048; i += 256){
      int co = i >> 5, pp = i & 31;
      oh[obase + ((size_t)co << 15) + pp] = (bf16_t)lo[co*33 + pp];
    }
  }
}

// --------------------------------------------------------------- coords passthrough
__global__ __launch_bounds__(256) void copy_coords_kernel(
    const void* __restrict__ coords, void* __restrict__ out, const int* __restrict__ flag){
  int i = blockIdx.x * 256 + threadIdx.x;
  if (i >= 786432) return;
  if (*flag) ((float*)out)[16777216 + i]  = ((const float*)coords)[i];
  else       ((bf16_t*)out)[16777216 + i] = ((const bf16_t*)coords)[i];
}

// --------------------------------------------------------------- param / weight prep
// fragment-major weight pack: dst[tap][ks][j][quad][lrow][e]
//   co = 16j + lrow, ci = ks*32 + quad*8 + e, lane = quad*16 + lrow
__global__ void prep_weights_kernel(const void* __restrict__ w1, const void* __restrict__ w2,
                                    const int* __restrict__ flag,
                                    bf16_t* __restrict__ wp1, bf16_t* __restrict__ wp2){
  int isf = *flag;
  int id = blockIdx.x * 256 + threadIdx.x;
  if (id >= 27*64*64) return;
  int off = id >> 12, co = (id >> 6) & 63, ci = id & 63;
  int src = (co*64 + ci)*27 + off;
  int j = co >> 4, lrow = co & 15;
  int ks = ci >> 5, quad = (ci >> 3) & 3, e = ci & 7;
  int dst = off*4096 + ks*2048 + j*512 + quad*128 + lrow*8 + e;
  wp1[dst] = (bf16_t)LD(w1, src, isf);
  wp2[dst] = (bf16_t)LD(w2, src, isf);
}

__global__ void prep_params_kernel(
    const void* c1b, const void* g1, const void* b1, const void* m1, const void* v1,
    const void* c2b, const void* g2, const void* b2, const void* m2, const void* v2,
    const void* pb_, const void* gp, const void* bp, const void* mp, const void* vp,
    const int* __restrict__ flag,
    float* __restrict__ P)   // [6][64]: s1, h1, s2, h2, sp, hp
{
  int isf = *flag;
  int c = threadIdx.x;
  if (c >= 64) return;
  float s1 = LD(g1,c,isf) / sqrtf(LD(v1,c,isf) + 1e-4f);
  P[c]       = s1;
  P[64 + c]  = (LD(c1b,c,isf) - LD(m1,c,isf))*s1 + LD(b1,c,isf);
  float s2 = LD(g2,c,isf) / sqrtf(LD(v2,c,isf) + 1e-4f);
  P[128 + c] = s2;
  P[192 + c] = (LD(c2b,c,isf) - LD(m2,c,isf))*s2 + LD(b2,c,isf);
  float sp = LD(gp,c,isf) / sqrtf(LD(vp,c,isf) + 1e-4f);
  P[256 + c] = sp;
  P[320 + c] = (LD(pb_,c,isf) - LD(mp,c,isf))*sp + LD(bp,c,isf);
}

// --------------------------------------------------------------- launch
extern "C" void kernel_launch(void* const* d_in, const int* in_sizes, int n_in,
                              void* d_out, int out_size, void* d_ws, size_t ws_size,
                              hipStream_t stream)
{
  const void* feat   = d_in[0];
  const void* coords = d_in[1];
  const void* c1w = d_in[2];
  const void* c1b = d_in[3];
  const void* g1  = d_in[4];
  const void* b1  = d_in[5];
  const void* m1  = d_in[6];
  const void* v1  = d_in[7];
  const void* c2w = d_in[8];
  const void* c2b = d_in[9];
  const void* g2  = d_in[10];
  const void* b2  = d_in[11];
  const void* m2  = d_in[12];
  const void* v2  = d_in[13];
  const void* mw  = d_in[14];
  const void* mb  = d_in[15];
  const void* gp  = d_in[16];
  const void* bp  = d_in[17];
  const void* mp  = d_in[18];
  const void* vp  = d_in[19];

  char* ws = (char*)d_ws;
  bf16_t*  feat_t  = (bf16_t*)(ws);                     // 33,554,432 B
  bf16_t*  vox     = (bf16_t*)(ws + 33554432);          // 33,554,432 B
  bf16_t*  c1out   = (bf16_t*)(ws + 67108864);          // 33,554,432 B
  bf16_t*  c2out   = vox;                               // vox dead after conv1
  uint2*   sorted  = (uint2*)(ws + 100663296);          // 16,777,216 B
  unsigned* hist   = (unsigned*)(ws + 117440512);       //  1,048,576 B
  unsigned* offs   = (unsigned*)(ws + 118489088);       //  1,048,576 B
  bf16_t*  wp1     = (bf16_t*)(ws + 119537664);         //    221,184 B
  bf16_t*  wp2     = (bf16_t*)(ws + 119758848);         //    221,184 B
  float*   P       = (float*)(ws + 119980032);          //      1,536 B
  float*   stats   = (float*)(ws + 119981568);          //        128 B
  int*     flag    = (int*)(ws + 119981696);            //        128 B
  unsigned* counter= (unsigned*)(ws + 119981824);       //        128 B
  float*   ssum    = (float*)(ws + 119981952);          //        128 B (8x4 f32)
  unsigned* smax   = (unsigned*)(ws + 119982080);       //        128 B

  hipMemsetAsync(flag, 0, 4, stream);
  hipMemsetAsync(hist, 0, 1048576, stream);
  hipMemsetAsync(counter, 0, 4, stream);
  hipMemsetAsync(ssum, 0, 256, stream);                 // ssum + smax
  detect_kernel<<<3072, 256, 0, stream>>>(coords, flag);
  prep_weights_kernel<<<432, 256, 0, stream>>>(c1w, c2w, flag, wp1, wp2);
  prep_params_kernel<<<1, 64, 0, stream>>>(c1b,g1,b1,m1,v1, c2b,g2,b2,m2,v2,
                                           mb,gp,bp,mp,vp, flag, P);
  stats_sum_kernel<<<256, 256, 0, stream>>>(coords, flag, ssum);
  stats_max_kernel<<<256, 256, 0, stream>>>(coords, flag, ssum, smax);
  stats_fin_kernel<<<1, 64, 0, stream>>>(ssum, smax, stats);
  transpose_kernel<<<4096, 256, 0, stream>>>(feat, flag, feat_t);
  hist_kernel<<<1024, 256, 0, stream>>>(coords, stats, flag, hist);
  offsets_kernel<<<1024, 256, 0, stream>>>(hist, offs, counter);
  fill_kernel<<<1024, 256, 0, stream>>>(coords, stats, flag, offs, sorted);
  gather_kernel<<<2048, 256, 0, stream>>>(sorted, offs, hist, feat_t, vox);
  conv3d_kernel<<<4096, 256, 0, stream>>>(vox,   wp1, P,       P + 64,  c1out);
  conv3d_kernel<<<4096, 256, 0, stream>>>(c1out, wp2, P + 128, P + 192, c2out);
  devox_kernel<<<8192, 256, 0, stream>>>(c2out, feat_t, coords, mw, stats, flag,
                                         P + 256, P + 320, d_out);
  copy_coords_kernel<<<3072, 256, 0, stream>>>(coords, d_out, flag);
}

// Round 5
// 893.832 us; speedup vs baseline: 1.1040x; 1.1040x over previous
//
#include <hip/hip_runtime.h>
#include <cstdint>
#include <cstddef>

#define NPTS  32768
#define NB    8
#define RR    32
#define RR3   32768
#define NVOX  (NB*RR3)          // 262144

typedef __bf16 bf16_t;
typedef __bf16 bf16x8 __attribute__((ext_vector_type(8)));
typedef __bf16 bf16x4 __attribute__((ext_vector_type(4)));
typedef float  f32x4  __attribute__((ext_vector_type(4)));

// adaptive load: input tensors may be fp32 or bf16 (detected at runtime)
__device__ __forceinline__ float LD(const void* p, size_t i, int isf){
  return isf ? ((const float*)p)[i] : (float)((const bf16_t*)p)[i];
}

// ---------------------------------------------------------------- reductions
__device__ __forceinline__ float wave_sum(float v){
#pragma unroll
  for (int o = 32; o > 0; o >>= 1) v += __shfl_down(v, o, 64);
  return v;
}
__device__ __forceinline__ float wave_max(float v){
#pragma unroll
  for (int o = 32; o > 0; o >>= 1) v = fmaxf(v, __shfl_down(v, o, 64));
  return v;
}

// --------------------------------------------------------------- dtype detect (parallel)
__global__ __launch_bounds__(256) void detect_kernel(const void* __restrict__ coords,
                                                     int* __restrict__ flag){
  int i = blockIdx.x*256 + threadIdx.x;
  const uint16_t* p = (const uint16_t*)coords;
  if ((p[i] & 0x7F80) == 0x7F80) atomicOr(flag, 1);   // 1 = fp32
}

// --------------------------------------------------------------- stats (3-phase parallel)
__global__ __launch_bounds__(256) void stats_sum_kernel(
    const void* __restrict__ coords, const int* __restrict__ flag, float* __restrict__ ssum){
  __shared__ float l[12];
  int isf = *flag;
  int b = blockIdx.x >> 5, blk = blockIdx.x & 31;     // 32 blocks per batch
  int t = threadIdx.x;
  size_t cb = ((size_t)b * 3) << 15;
  float sx = 0.f, sy = 0.f, sz = 0.f;
  int n0 = blk << 10;
  for (int n = n0 + t; n < n0 + 1024; n += 256){
    sx += LD(coords, cb + n, isf);
    sy += LD(coords, cb + NPTS + n, isf);
    sz += LD(coords, cb + 2*NPTS + n, isf);
  }
  sx = wave_sum(sx); sy = wave_sum(sy); sz = wave_sum(sz);
  int w = t >> 6;
  if ((t & 63) == 0){ l[w] = sx; l[4+w] = sy; l[8+w] = sz; }
  __syncthreads();
  if (t == 0){
    unsafeAtomicAdd(&ssum[b*4+0], l[0]+l[1]+l[2]+l[3]);
    unsafeAtomicAdd(&ssum[b*4+1], l[4]+l[5]+l[6]+l[7]);
    unsafeAtomicAdd(&ssum[b*4+2], l[8]+l[9]+l[10]+l[11]);
  }
}

__global__ __launch_bounds__(256) void stats_max_kernel(
    const void* __restrict__ coords, const int* __restrict__ flag,
    const float* __restrict__ ssum, unsigned* __restrict__ smax){
  __shared__ float l[4];
  int isf = *flag;
  int b = blockIdx.x >> 5, blk = blockIdx.x & 31;
  int t = threadIdx.x;
  size_t cb = ((size_t)b * 3) << 15;
  float mx = ssum[b*4+0] * (1.f/NPTS);
  float my = ssum[b*4+1] * (1.f/NPTS);
  float mz = ssum[b*4+2] * (1.f/NPTS);
  float mm = 0.f;
  int n0 = blk << 10;
  for (int n = n0 + t; n < n0 + 1024; n += 256){
    float cx = LD(coords, cb + n, isf) - mx;
    float cy = LD(coords, cb + NPTS + n, isf) - my;
    float cz = LD(coords, cb + 2*NPTS + n, isf) - mz;
    mm = fmaxf(mm, cx*cx + cy*cy + cz*cz);
  }
  mm = wave_max(mm);
  int w = t >> 6;
  if ((t & 63) == 0) l[w] = mm;
  __syncthreads();
  if (t == 0){
    float m = fmaxf(fmaxf(l[0], l[1]), fmaxf(l[2], l[3]));
    atomicMax(&smax[b], __float_as_uint(m));          // valid: m >= 0
  }
}

__global__ void stats_fin_kernel(const float* __restrict__ ssum,
                                 const unsigned* __restrict__ smax,
                                 float* __restrict__ stats){
  int b = threadIdx.x;
  if (b >= NB) return;
  float m = __uint_as_float(smax[b]);
  float inv = 32.f / (2.f * sqrtf(m) * (1.f + 1e-6f));
  float4 o;
  o.x = ssum[b*4+0] * (1.f/NPTS);
  o.y = ssum[b*4+1] * (1.f/NPTS);
  o.z = ssum[b*4+2] * (1.f/NPTS);
  o.w = inv;
  ((float4*)stats)[b] = o;
}

// --------------------------------------------------------------- corners
__device__ __forceinline__ void compute_corners(const void* __restrict__ coords, float4 st,
                                                int b, int n, int isf, int* idx, float* wts){
  size_t cbase = ((size_t)b * 3) << 15;
  float cx = LD(coords, cbase + n, isf)          - st.x;
  float cy = LD(coords, cbase + NPTS + n, isf)   - st.y;
  float cz = LD(coords, cbase + 2*NPTS + n, isf) - st.z;
  float vx = fminf(fmaxf(cx*st.w + 16.f, 0.f), 31.f);
  float vy = fminf(fmaxf(cy*st.w + 16.f, 0.f), 31.f);
  float vz = fminf(fmaxf(cz*st.w + 16.f, 0.f), 31.f);
  int lx = (int)vx, ly = (int)vy, lz = (int)vz;
  float fx = vx - (float)lx, fy = vy - (float)ly, fz = vz - (float)lz;
#pragma unroll
  for (int k = 0; k < 8; ++k){
    int dx = k >> 2, dy = (k >> 1) & 1, dz = k & 1;
    int xi = min(lx+dx, 31), yi = min(ly+dy, 31), zi = min(lz+dz, 31);
    idx[k] = (xi << 10) + (yi << 5) + zi;
    wts[k] = (dx ? fx : 1.f-fx) * (dy ? fy : 1.f-fy) * (dz ? fz : 1.f-fz);
  }
}

// --------------------------------------------------------------- transpose feat -> [B*N,64] bf16
__global__ __launch_bounds__(256) void transpose_kernel(
    const void* __restrict__ feat, const int* __restrict__ flag, bf16_t* __restrict__ feat_t)
{
  __shared__ float tile[64][65];
  int isf = *flag;
  int blk = blockIdx.x;            // 4096 = B * (N/64)
  int b = blk >> 9;
  int n0 = (blk & 511) << 6;
  int t = threadIdx.x, lane = t & 63, w = t >> 6;
  size_t base = ((size_t)b << 21); // b*64*N
  for (int ci = w; ci < 64; ci += 4)
    tile[ci][lane] = LD(feat, base + ((size_t)ci << 15) + n0 + lane, isf);
  __syncthreads();
  for (int i = t; i < 512; i += 256){
    int p = i >> 3, seg = i & 7;
    bf16x8 o;
#pragma unroll
    for (int e = 0; e < 8; ++e) o[e] = (bf16_t)tile[seg*8+e][p];
    *(bf16x8*)(feat_t + (((size_t)(b*NPTS + n0 + p)) << 6) + seg*8) = o;
  }
}

// --------------------------------------------------------------- voxelize: hist / offsets / fill / gather
__global__ __launch_bounds__(256) void hist_kernel(
    const void* __restrict__ coords, const float* __restrict__ stats,
    const int* __restrict__ flag, unsigned* __restrict__ hist)
{
  int isf = *flag;
  int gid = blockIdx.x*256 + threadIdx.x;
  int b = gid >> 15, n = gid & (NPTS-1);
  float4 st = ((const float4*)stats)[b];
  int idx[8]; float wts[8];
  compute_corners(coords, st, b, n, isf, idx, wts);
#pragma unroll
  for (int k = 0; k < 8; ++k) atomicAdd(&hist[(b << 15) + idx[k]], 1u);
}

__global__ __launch_bounds__(256) void offsets_kernel(
    const unsigned* __restrict__ hist, unsigned* __restrict__ offsets,
    unsigned* __restrict__ counter)
{
  int v = blockIdx.x*256 + threadIdx.x;
  int lane = threadIdx.x & 63;
  unsigned h = hist[v];
  unsigned pre = h;
#pragma unroll
  for (int o = 1; o < 64; o <<= 1){
    unsigned x = __shfl_up(pre, o, 64);
    if (lane >= o) pre += x;
  }
  unsigned total = __shfl(pre, 63, 64);
  unsigned base = 0;
  if (lane == 63) base = atomicAdd(counter, total);
  base = __shfl(base, 63, 64);
  offsets[v] = base + pre - h;      // exclusive start of segment v
}

__global__ __launch_bounds__(256) void fill_kernel(
    const void* __restrict__ coords, const float* __restrict__ stats,
    const int* __restrict__ flag, unsigned* __restrict__ offsets,
    uint2* __restrict__ sorted)
{
  int isf = *flag;
  int gid = blockIdx.x*256 + threadIdx.x;
  int b = gid >> 15, n = gid & (NPTS-1);
  float4 st = ((const float4*)stats)[b];
  int idx[8]; float wts[8];
  compute_corners(coords, st, b, n, isf, idx, wts);
#pragma unroll
  for (int k = 0; k < 8; ++k){
    unsigned pos = atomicAdd(&offsets[(b << 15) + idx[k]], 1u);   // bumps to segment end
    sorted[pos] = make_uint2((unsigned)n, __float_as_uint(wts[k]));
  }
}

// PERSISTENT gather, SCATTERED assignment: 2048 blocks x 4 waves = 8192 waves
// (exactly 32 waves/CU). Wave w handles voxels v = ((w*32+k)*M) & (NVOX-1),
// k=0..31, M odd -> bijection mod 2^18 that scatters each wave's voxels across
// x, y, z AND batch. (Round-4's v += 8192 kept v mod 8192 constant per wave,
// so one wave owned the entire dense Gaussian-center (y,z) column -> 80us
// straggler tail, occupancy 15%.)
// Per voxel: lane = g*8 + c8 (8 entry slots x 8 channels of 16B).
// cnt==0 fast path; unpredicated 64-entry blocks; predicated 16-entry tail.
__global__ __launch_bounds__(256) void gather_kernel(
    const uint2* __restrict__ sorted, const unsigned* __restrict__ offsets_end,
    const unsigned* __restrict__ hist, const bf16_t* __restrict__ feat_t,
    bf16_t* __restrict__ vox)
{
  const unsigned M = 162005u;          // odd -> bijective scatter mod 2^18
  int wid = blockIdx.x*4 + (threadIdx.x >> 6);
  int lane = threadIdx.x & 63;
  int g  = lane >> 3;                  // entry slot group
  int c8 = lane & 7;                   // 8 bf16 channels (16B) per lane

#pragma unroll 1
  for (int k = 0; k < 32; ++k){
    int v = (int)((((unsigned)wid << 5) | (unsigned)k) * M & (NVOX - 1u));
    unsigned end = offsets_end[v];
    unsigned cnt = hist[v];
    if (cnt == 0){
      if (g == 0){
        bf16x8 z;
#pragma unroll
        for (int j = 0; j < 8; ++j) z[j] = (bf16_t)0.f;
        *(bf16x8*)(vox + ((size_t)v << 6) + c8*8) = z;
      }
      continue;
    }
    int b = v >> 15;
    size_t fbase = ((size_t)b << 21);  // b*NPTS*64
    unsigned base = end - cnt;
    float acc[8] = {0.f,0.f,0.f,0.f,0.f,0.f,0.f,0.f};
    float cw = 0.f;
    // ---- full 64-entry blocks (unpredicated) ----
    for (; base + 64 <= end; base += 64){
      uint2 e[8];
#pragma unroll
      for (int d = 0; d < 8; ++d) e[d] = sorted[base + g + 8*d];
      bf16x8 f[8];
#pragma unroll
      for (int d = 0; d < 8; ++d)
        f[d] = *(const bf16x8*)(feat_t + fbase + ((size_t)e[d].x << 6) + c8*8);
#pragma unroll
      for (int d = 0; d < 8; ++d){
        float w = __uint_as_float(e[d].y);
#pragma unroll
        for (int j = 0; j < 8; ++j) acc[j] += w * (float)f[d][j];
        cw += w;
      }
    }
    // ---- 16-entry tail (predicated, depth 2) ----
    for (; base < end; base += 16){
      unsigned i0 = base + g, i1 = base + g + 8;
      uint2 e0 = (i0 < end) ? sorted[i0] : make_uint2(0u, 0u);
      uint2 e1 = (i1 < end) ? sorted[i1] : make_uint2(0u, 0u);
      bf16x8 f0 = *(const bf16x8*)(feat_t + fbase + ((size_t)e0.x << 6) + c8*8);
      bf16x8 f1 = *(const bf16x8*)(feat_t + fbase + ((size_t)e1.x << 6) + c8*8);
      float w0 = __uint_as_float(e0.y), w1 = __uint_as_float(e1.y);
#pragma unroll
      for (int j = 0; j < 8; ++j) acc[j] += w0 * (float)f0[j] + w1 * (float)f1[j];
      cw += w0 + w1;
    }
    // combine the 8 entry-slot groups (lanes differing in bits 3,4,5)
#pragma unroll
    for (int m = 8; m < 64; m <<= 1){
#pragma unroll
      for (int j = 0; j < 8; ++j) acc[j] += __shfl_xor(acc[j], m, 64);
      cw += __shfl_xor(cw, m, 64);
    }
    if (g == 0){
      float inv = 1.f / fmaxf(cw, 1e-8f);
      bf16x8 o;
#pragma unroll
      for (int j = 0; j < 8; ++j) o[j] = (bf16_t)(acc[j]*inv);
      *(bf16x8*)(vox + ((size_t)v << 6) + c8*8) = o;
    }
  }
}

// --------------------------------------------------------------- conv3d 3x3x3 + BN + LeakyReLU
// channels-last in/out [B*R3, 64]; tile: x fixed, y0..y0+3, z0..z0+15 (64 voxels / wg).
// Weights are consumed as per-wave REGISTER fragments loaded straight from a
// fragment-major pack [27][ks=2][j=4][lane=64] (16B/lane, coalesced, L2-hot),
// 3-buffer rotation prefetching 2 taps ahead -> ZERO barriers in the tap loop.
// Input tile: true 128B rows, T2-style XOR swizzle (chunk ^= row&7) on both the
// staging write and the fragment read -> conflict-free ds_read_b128.
struct W8 { bf16x8 v[8]; };

__device__ __forceinline__ void load_wfrag(const bf16_t* __restrict__ wpack, int tap, int lane, W8& w){
#pragma unroll
  for (int f = 0; f < 8; ++f)
    w.v[f] = *(const bf16x8*)(wpack + (size_t)(tap*8 + f)*512 + lane*8);
}

__device__ __forceinline__ void tap_mfma(const bf16_t* lds_in, int rowidx, int quad, const W8& w,
                                         f32x4& a0, f32x4& a1, f32x4& a2, f32x4& a3){
  int swz = rowidx & 7;
#pragma unroll
  for (int ks = 0; ks < 2; ++ks){
    bf16x8 a = *(const bf16x8*)(lds_in + rowidx*64 + ((((ks<<2)|quad) ^ swz) << 3));
    a0 = __builtin_amdgcn_mfma_f32_16x16x32_bf16(a, w.v[ks*4+0], a0, 0, 0, 0);
    a1 = __builtin_amdgcn_mfma_f32_16x16x32_bf16(a, w.v[ks*4+1], a1, 0, 0, 0);
    a2 = __builtin_amdgcn_mfma_f32_16x16x32_bf16(a, w.v[ks*4+2], a2, 0, 0, 0);
    a3 = __builtin_amdgcn_mfma_f32_16x16x32_bf16(a, w.v[ks*4+3], a3, 0, 0, 0);
  }
}

__global__ __launch_bounds__(256, 3) void conv3d_kernel(
    const bf16_t* __restrict__ in, const bf16_t* __restrict__ wpack,   // frag-major [27][2][4][64][8]
    const float* __restrict__ scale, const float* __restrict__ shift,
    bf16_t* __restrict__ out)
{
  __shared__ bf16_t lds_in[324*64];      // 41,472 B, XOR-swizzled 128B rows
  int bid = blockIdx.x;
  int b  = bid >> 9;
  int x  = (bid >> 4) & 31;
  int y0 = ((bid >> 1) & 7) << 2;
  int z0 = (bid & 1) << 4;
  int t = threadIdx.x;
  for (int seg = t; seg < 324*8; seg += 256){
    int row = seg >> 3, part = seg & 7;
    int hx = row / 108, rem = row - hx*108;
    int hy = rem / 18,  hz = rem - hy*18;
    int gx = x + hx - 1, gy = y0 + hy - 1, gz = z0 + hz - 1;
    uint4 val = make_uint4(0u,0u,0u,0u);
    if ((unsigned)gx < 32u && (unsigned)gy < 32u && (unsigned)gz < 32u)
      val = *(const uint4*)(in + ((((size_t)(b*RR3 + ((gx<<10)+(gy<<5)+gz))) << 6) + part*8));
    *(uint4*)(lds_in + row*64 + ((part ^ (row & 7)) << 3)) = val;
  }
  int wave = t >> 6, lane = t & 63;
  int lrow = lane & 15, quad = lane >> 4;
  int rowbase = wave*18 + lrow;          // + dx*108 + dy*18 + dz per tap
  f32x4 acc0 = 0.f, acc1 = 0.f, acc2 = 0.f, acc3 = 0.f;

  W8 wA, wB, wC;
  load_wfrag(wpack, 0, lane, wA);        // prefetch tap 0
  load_wfrag(wpack, 1, lane, wB);        // prefetch tap 1
  __syncthreads();                       // only barrier: input tile ready

#pragma unroll
  for (int p = 0; p < 9; ++p){
    int t0 = 3*p, t1 = 3*p+1, t2 = 3*p+2;
    int n0 = (t0+2 < 27) ? t0+2 : 26;
    int n1 = (t1+2 < 27) ? t1+2 : 26;
    int n2 = (t2+2 < 27) ? t2+2 : 26;
    load_wfrag(wpack, n0, lane, wC);
    { int dx = t0/9, r9 = t0-dx*9, dy = r9/3, dz = r9-dy*3;
      tap_mfma(lds_in, rowbase + dx*108 + dy*18 + dz, quad, wA, acc0, acc1, acc2, acc3); }
    load_wfrag(wpack, n1, lane, wA);
    { int dx = t1/9, r9 = t1-dx*9, dy = r9/3, dz = r9-dy*3;
      tap_mfma(lds_in, rowbase + dx*108 + dy*18 + dz, quad, wB, acc0, acc1, acc2, acc3); }
    load_wfrag(wpack, n2, lane, wB);
    { int dx = t2/9, r9 = t2-dx*9, dy = r9/3, dz = r9-dy*3;
      tap_mfma(lds_in, rowbase + dx*108 + dy*18 + dz, quad, wC, acc0, acc1, acc2, acc3); }
  }

  f32x4 accs[4] = {acc0, acc1, acc2, acc3};
#pragma unroll
  for (int j = 0; j < 4; ++j){
    int co = j*16 + lrow;
    float sc = scale[co], sh = shift[co];
#pragma unroll
    for (int r = 0; r < 4; ++r){
      int zl = quad*4 + r;
      size_t o = (((size_t)(b*RR3 + ((x<<10) + ((y0+wave)<<5) + z0 + zl))) << 6) + co;
      float val = accs[j][r]*sc + sh;
      val = fmaxf(val, 0.1f*val);                    // LeakyReLU(0.1)
      out[o] = (bf16_t)val;
    }
  }
}

// --------------------------------------------------------------- devoxelize + point branch
__global__ __launch_bounds__(256) void devox_kernel(
    const bf16_t* __restrict__ g,        // conv2 out [B*R3,64] channels-last
    const bf16_t* __restrict__ feat_t,   // [B*N,64] bf16 point-major
    const void* __restrict__ coords,
    const void* __restrict__ mlp_w,      // [64,64]
    const float* __restrict__ stats, const int* __restrict__ flag,
    const float* __restrict__ pscale, const float* __restrict__ pshift,
    void* __restrict__ out)              // [B,64,N]
{
  __shared__ bf16_t lf[32*72];           // feat tile [p][ci]
  __shared__ bf16_t lw[64*64];           // mlp_w [o][c]
  __shared__ float  lo[64*33];           // out tile [co][p]
  int t = threadIdx.x;
  int isf = *flag;
  int pb = blockIdx.x << 5;              // 32 points / block
  int b = pb >> 15, n0 = pb & (NPTS - 1);
  {
    int p = t >> 3, seg = t & 7;         // 256 threads == 32 points x 8 segs
    *(bf16x8*)(lf + p*72 + seg*8) =
        *(const bf16x8*)(feat_t + (((size_t)(b*NPTS + n0 + p)) << 6) + seg*8);
  }
  for (int i = t; i < 4096; i += 256)
    lw[i] = (bf16_t)LD(mlp_w, i, isf);
  __syncthreads();
  int p = t >> 3, gseg = t & 7;
  int n = n0 + p;
  float4 st = ((const float4*)stats)[b];
  int idx[8]; float wts[8];
  compute_corners(coords, st, b, n, isf, idx, wts);
  float dv[8] = {0,0,0,0,0,0,0,0};
#pragma unroll
  for (int k = 0; k < 8; ++k){
    bf16x8 gv = *(const bf16x8*)(g + (((size_t)(b*RR3 + idx[k])) << 6) + gseg*8);
    float w = wts[k];
#pragma unroll
    for (int j = 0; j < 8; ++j) dv[j] += w * (float)gv[j];
  }
  float pv[8] = {0,0,0,0,0,0,0,0};
#pragma unroll
  for (int s = 0; s < 8; ++s){
    bf16x8 fv = *(const bf16x8*)(lf + p*72 + s*8);
    float fvf[8];
#pragma unroll
    for (int e = 0; e < 8; ++e) fvf[e] = (float)fv[e];
#pragma unroll
    for (int j = 0; j < 8; ++j){
      bf16x8 wv = *(const bf16x8*)(lw + (gseg*8 + j)*64 + s*8);
#pragma unroll
      for (int e = 0; e < 8; ++e) pv[j] += (float)wv[e] * fvf[e];
    }
  }
#pragma unroll
  for (int j = 0; j < 8; ++j){
    int co = gseg*8 + j;
    float q = pv[j]*pscale[co] + pshift[co];
    q = fmaxf(q, 0.f);
    lo[co*33 + p] = dv[j] + q;
  }
  __syncthreads();
  size_t obase = ((size_t)b << 21) + n0;
  if (isf){
    float* of = (float*)out;
    for (int i = t; i < 2048; i += 256){
      int co = i >> 5, pp = i & 31;
      of[obase + ((size_t)co << 15) + pp] = lo[co*33 + pp];
    }
  } else {
    bf16_t* oh = (bf16_t*)out;
    for (int i = t; i < 2048; i += 256){
      int co = i >> 5, pp = i & 31;
      oh[obase + ((size_t)co << 15) + pp] = (bf16_t)lo[co*33 + pp];
    }
  }
}

// --------------------------------------------------------------- coords passthrough
__global__ __launch_bounds__(256) void copy_coords_kernel(
    const void* __restrict__ coords, void* __restrict__ out, const int* __restrict__ flag){
  int i = blockIdx.x * 256 + threadIdx.x;
  if (i >= 786432) return;
  if (*flag) ((float*)out)[16777216 + i]  = ((const float*)coords)[i];
  else       ((bf16_t*)out)[16777216 + i] = ((const bf16_t*)coords)[i];
}

// --------------------------------------------------------------- param / weight prep
// fragment-major weight pack: dst[tap][ks][j][quad][lrow][e]
//   co = 16j + lrow, ci = ks*32 + quad*8 + e, lane = quad*16 + lrow
__global__ void prep_weights_kernel(const void* __restrict__ w1, const void* __restrict__ w2,
                                    const int* __restrict__ flag,
                                    bf16_t* __restrict__ wp1, bf16_t* __restrict__ wp2){
  int isf = *flag;
  int id = blockIdx.x * 256 + threadIdx.x;
  if (id >= 27*64*64) return;
  int off = id >> 12, co = (id >> 6) & 63, ci = id & 63;
  int src = (co*64 + ci)*27 + off;
  int j = co >> 4, lrow = co & 15;
  int ks = ci >> 5, quad = (ci >> 3) & 3, e = ci & 7;
  int dst = off*4096 + ks*2048 + j*512 + quad*128 + lrow*8 + e;
  wp1[dst] = (bf16_t)LD(w1, src, isf);
  wp2[dst] = (bf16_t)LD(w2, src, isf);
}

__global__ void prep_params_kernel(
    const void* c1b, const void* g1, const void* b1, const void* m1, const void* v1,
    const void* c2b, const void* g2, const void* b2, const void* m2, const void* v2,
    const void* pb_, const void* gp, const void* bp, const void* mp, const void* vp,
    const int* __restrict__ flag,
    float* __restrict__ P)   // [6][64]: s1, h1, s2, h2, sp, hp
{
  int isf = *flag;
  int c = threadIdx.x;
  if (c >= 64) return;
  float s1 = LD(g1,c,isf) / sqrtf(LD(v1,c,isf) + 1e-4f);
  P[c]       = s1;
  P[64 + c]  = (LD(c1b,c,isf) - LD(m1,c,isf))*s1 + LD(b1,c,isf);
  float s2 = LD(g2,c,isf) / sqrtf(LD(v2,c,isf) + 1e-4f);
  P[128 + c] = s2;
  P[192 + c] = (LD(c2b,c,isf) - LD(m2,c,isf))*s2 + LD(b2,c,isf);
  float sp = LD(gp,c,isf) / sqrtf(LD(vp,c,isf) + 1e-4f);
  P[256 + c] = sp;
  P[320 + c] = (LD(pb_,c,isf) - LD(mp,c,isf))*sp + LD(bp,c,isf);
}

// --------------------------------------------------------------- launch
extern "C" void kernel_launch(void* const* d_in, const int* in_sizes, int n_in,
                              void* d_out, int out_size, void* d_ws, size_t ws_size,
                              hipStream_t stream)
{
  const void* feat   = d_in[0];
  const void* coords = d_in[1];
  const void* c1w = d_in[2];
  const void* c1b = d_in[3];
  const void* g1  = d_in[4];
  const void* b1  = d_in[5];
  const void* m1  = d_in[6];
  const void* v1  = d_in[7];
  const void* c2w = d_in[8];
  const void* c2b = d_in[9];
  const void* g2  = d_in[10];
  const void* b2  = d_in[11];
  const void* m2  = d_in[12];
  const void* v2  = d_in[13];
  const void* mw  = d_in[14];
  const void* mb  = d_in[15];
  const void* gp  = d_in[16];
  const void* bp  = d_in[17];
  const void* mp  = d_in[18];
  const void* vp  = d_in[19];

  char* ws = (char*)d_ws;
  bf16_t*  feat_t  = (bf16_t*)(ws);                     // 33,554,432 B
  bf16_t*  vox     = (bf16_t*)(ws + 33554432);          // 33,554,432 B
  bf16_t*  c1out   = (bf16_t*)(ws + 67108864);          // 33,554,432 B
  bf16_t*  c2out   = vox;                               // vox dead after conv1
  uint2*   sorted  = (uint2*)(ws + 100663296);          // 16,777,216 B
  unsigned* hist   = (unsigned*)(ws + 117440512);       //  1,048,576 B
  unsigned* offs   = (unsigned*)(ws + 118489088);       //  1,048,576 B
  bf16_t*  wp1     = (bf16_t*)(ws + 119537664);         //    221,184 B
  bf16_t*  wp2     = (bf16_t*)(ws + 119758848);         //    221,184 B
  float*   P       = (float*)(ws + 119980032);          //      1,536 B
  float*   stats   = (float*)(ws + 119981568);          //        128 B
  int*     flag    = (int*)(ws + 119981696);            //        128 B
  unsigned* counter= (unsigned*)(ws + 119981824);       //        128 B
  float*   ssum    = (float*)(ws + 119981952);          //        128 B (8x4 f32)
  unsigned* smax   = (unsigned*)(ws + 119982080);       //        128 B

  hipMemsetAsync(flag, 0, 4, stream);
  hipMemsetAsync(hist, 0, 1048576, stream);
  hipMemsetAsync(counter, 0, 4, stream);
  hipMemsetAsync(ssum, 0, 256, stream);                 // ssum + smax
  detect_kernel<<<3072, 256, 0, stream>>>(coords, flag);
  prep_weights_kernel<<<432, 256, 0, stream>>>(c1w, c2w, flag, wp1, wp2);
  prep_params_kernel<<<1, 64, 0, stream>>>(c1b,g1,b1,m1,v1, c2b,g2,b2,m2,v2,
                                           mb,gp,bp,mp,vp, flag, P);
  stats_sum_kernel<<<256, 256, 0, stream>>>(coords, flag, ssum);
  stats_max_kernel<<<256, 256, 0, stream>>>(coords, flag, ssum, smax);
  stats_fin_kernel<<<1, 64, 0, stream>>>(ssum, smax, stats);
  transpose_kernel<<<4096, 256, 0, stream>>>(feat, flag, feat_t);
  hist_kernel<<<1024, 256, 0, stream>>>(coords, stats, flag, hist);
  offsets_kernel<<<1024, 256, 0, stream>>>(hist, offs, counter);
  fill_kernel<<<1024, 256, 0, stream>>>(coords, stats, flag, offs, sorted);
  gather_kernel<<<2048, 256, 0, stream>>>(sorted, offs, hist, feat_t, vox);
  conv3d_kernel<<<4096, 256, 0, stream>>>(vox,   wp1, P,       P + 64,  c1out);
  conv3d_kernel<<<4096, 256, 0, stream>>>(c1out, wp2, P + 128, P + 192, c2out);
  devox_kernel<<<8192, 256, 0, stream>>>(c2out, feat_t, coords, mw, stats, flag,
                                         P + 256, P + 320, d_out);
  copy_coords_kernel<<<3072, 256, 0, stream>>>(coords, d_out, flag);
}

// Round 7
// 801.938 us; speedup vs baseline: 1.2305x; 1.1146x over previous
//
#include <hip/hip_runtime.h>
#include <cstdint>
#include <cstddef>

#define NPTS  32768
#define NB    8
#define RR    32
#define RR3   32768
#define NVOX  (NB*RR3)          // 262144

typedef __bf16 bf16_t;
typedef __bf16 bf16x8 __attribute__((ext_vector_type(8)));
typedef __bf16 bf16x4 __attribute__((ext_vector_type(4)));
typedef float  f32x4  __attribute__((ext_vector_type(4)));

// adaptive load: input tensors may be fp32 or bf16 (detected at runtime)
__device__ __forceinline__ float LD(const void* p, size_t i, int isf){
  return isf ? ((const float*)p)[i] : (float)((const bf16_t*)p)[i];
}

// ---------------------------------------------------------------- reductions
__device__ __forceinline__ float wave_sum(float v){
#pragma unroll
  for (int o = 32; o > 0; o >>= 1) v += __shfl_down(v, o, 64);
  return v;
}
__device__ __forceinline__ float wave_max(float v){
#pragma unroll
  for (int o = 32; o > 0; o >>= 1) v = fmaxf(v, __shfl_down(v, o, 64));
  return v;
}

// --------------------------------------------------------------- dtype detect (parallel)
__global__ __launch_bounds__(256) void detect_kernel(const void* __restrict__ coords,
                                                     int* __restrict__ flag){
  int i = blockIdx.x*256 + threadIdx.x;
  const uint16_t* p = (const uint16_t*)coords;
  if ((p[i] & 0x7F80) == 0x7F80) atomicOr(flag, 1);   // 1 = fp32
}

// --------------------------------------------------------------- stats (3-phase parallel)
__global__ __launch_bounds__(256) void stats_sum_kernel(
    const void* __restrict__ coords, const int* __restrict__ flag, float* __restrict__ ssum){
  __shared__ float l[12];
  int isf = *flag;
  int b = blockIdx.x >> 5, blk = blockIdx.x & 31;     // 32 blocks per batch
  int t = threadIdx.x;
  size_t cb = ((size_t)b * 3) << 15;
  float sx = 0.f, sy = 0.f, sz = 0.f;
  int n0 = blk << 10;
  for (int n = n0 + t; n < n0 + 1024; n += 256){
    sx += LD(coords, cb + n, isf);
    sy += LD(coords, cb + NPTS + n, isf);
    sz += LD(coords, cb + 2*NPTS + n, isf);
  }
  sx = wave_sum(sx); sy = wave_sum(sy); sz = wave_sum(sz);
  int w = t >> 6;
  if ((t & 63) == 0){ l[w] = sx; l[4+w] = sy; l[8+w] = sz; }
  __syncthreads();
  if (t == 0){
    unsafeAtomicAdd(&ssum[b*4+0], l[0]+l[1]+l[2]+l[3]);
    unsafeAtomicAdd(&ssum[b*4+1], l[4]+l[5]+l[6]+l[7]);
    unsafeAtomicAdd(&ssum[b*4+2], l[8]+l[9]+l[10]+l[11]);
  }
}

__global__ __launch_bounds__(256) void stats_max_kernel(
    const void* __restrict__ coords, const int* __restrict__ flag,
    const float* __restrict__ ssum, unsigned* __restrict__ smax){
  __shared__ float l[4];
  int isf = *flag;
  int b = blockIdx.x >> 5, blk = blockIdx.x & 31;
  int t = threadIdx.x;
  size_t cb = ((size_t)b * 3) << 15;
  float mx = ssum[b*4+0] * (1.f/NPTS);
  float my = ssum[b*4+1] * (1.f/NPTS);
  float mz = ssum[b*4+2] * (1.f/NPTS);
  float mm = 0.f;
  int n0 = blk << 10;
  for (int n = n0 + t; n < n0 + 1024; n += 256){
    float cx = LD(coords, cb + n, isf) - mx;
    float cy = LD(coords, cb + NPTS + n, isf) - my;
    float cz = LD(coords, cb + 2*NPTS + n, isf) - mz;
    mm = fmaxf(mm, cx*cx + cy*cy + cz*cz);
  }
  mm = wave_max(mm);
  int w = t >> 6;
  if ((t & 63) == 0) l[w] = mm;
  __syncthreads();
  if (t == 0){
    float m = fmaxf(fmaxf(l[0], l[1]), fmaxf(l[2], l[3]));
    atomicMax(&smax[b], __float_as_uint(m));          // valid: m >= 0
  }
}

__global__ void stats_fin_kernel(const float* __restrict__ ssum,
                                 const unsigned* __restrict__ smax,
                                 float* __restrict__ stats){
  int b = threadIdx.x;
  if (b >= NB) return;
  float m = __uint_as_float(smax[b]);
  float inv = 32.f / (2.f * sqrtf(m) * (1.f + 1e-6f));
  float4 o;
  o.x = ssum[b*4+0] * (1.f/NPTS);
  o.y = ssum[b*4+1] * (1.f/NPTS);
  o.z = ssum[b*4+2] * (1.f/NPTS);
  o.w = inv;
  ((float4*)stats)[b] = o;
}

// --------------------------------------------------------------- corners
__device__ __forceinline__ void compute_corners(const void* __restrict__ coords, float4 st,
                                                int b, int n, int isf, int* idx, float* wts){
  size_t cbase = ((size_t)b * 3) << 15;
  float cx = LD(coords, cbase + n, isf)          - st.x;
  float cy = LD(coords, cbase + NPTS + n, isf)   - st.y;
  float cz = LD(coords, cbase + 2*NPTS + n, isf) - st.z;
  float vx = fminf(fmaxf(cx*st.w + 16.f, 0.f), 31.f);
  float vy = fminf(fmaxf(cy*st.w + 16.f, 0.f), 31.f);
  float vz = fminf(fmaxf(cz*st.w + 16.f, 0.f), 31.f);
  int lx = (int)vx, ly = (int)vy, lz = (int)vz;
  float fx = vx - (float)lx, fy = vy - (float)ly, fz = vz - (float)lz;
#pragma unroll
  for (int k = 0; k < 8; ++k){
    int dx = k >> 2, dy = (k >> 1) & 1, dz = k & 1;
    int xi = min(lx+dx, 31), yi = min(ly+dy, 31), zi = min(lz+dz, 31);
    idx[k] = (xi << 10) + (yi << 5) + zi;
    wts[k] = (dx ? fx : 1.f-fx) * (dy ? fy : 1.f-fy) * (dz ? fz : 1.f-fz);
  }
}

// --------------------------------------------------------------- transpose feat -> [B*N,64] bf16
__global__ __launch_bounds__(256) void transpose_kernel(
    const void* __restrict__ feat, const int* __restrict__ flag, bf16_t* __restrict__ feat_t)
{
  __shared__ float tile[64][65];
  int isf = *flag;
  int blk = blockIdx.x;            // 4096 = B * (N/64)
  int b = blk >> 9;
  int n0 = (blk & 511) << 6;
  int t = threadIdx.x, lane = t & 63, w = t >> 6;
  size_t base = ((size_t)b << 21); // b*64*N
  for (int ci = w; ci < 64; ci += 4)
    tile[ci][lane] = LD(feat, base + ((size_t)ci << 15) + n0 + lane, isf);
  __syncthreads();
  for (int i = t; i < 512; i += 256){
    int p = i >> 3, seg = i & 7;
    bf16x8 o;
#pragma unroll
    for (int e = 0; e < 8; ++e) o[e] = (bf16_t)tile[seg*8+e][p];
    *(bf16x8*)(feat_t + (((size_t)(b*NPTS + n0 + p)) << 6) + seg*8) = o;
  }
}

// --------------------------------------------------------------- voxelize: hist / offsets / fill / gather
__global__ __launch_bounds__(256) void hist_kernel(
    const void* __restrict__ coords, const float* __restrict__ stats,
    const int* __restrict__ flag, unsigned* __restrict__ hist)
{
  int isf = *flag;
  int gid = blockIdx.x*256 + threadIdx.x;
  int b = gid >> 15, n = gid & (NPTS-1);
  float4 st = ((const float4*)stats)[b];
  int idx[8]; float wts[8];
  compute_corners(coords, st, b, n, isf, idx, wts);
#pragma unroll
  for (int k = 0; k < 8; ++k) atomicAdd(&hist[(b << 15) + idx[k]], 1u);
}

__global__ __launch_bounds__(256) void offsets_kernel(
    const unsigned* __restrict__ hist, unsigned* __restrict__ offsets,
    unsigned* __restrict__ counter)
{
  int v = blockIdx.x*256 + threadIdx.x;
  int lane = threadIdx.x & 63;
  unsigned h = hist[v];
  unsigned pre = h;
#pragma unroll
  for (int o = 1; o < 64; o <<= 1){
    unsigned x = __shfl_up(pre, o, 64);
    if (lane >= o) pre += x;
  }
  unsigned total = __shfl(pre, 63, 64);
  unsigned base = 0;
  if (lane == 63) base = atomicAdd(counter, total);
  base = __shfl(base, 63, 64);
  offsets[v] = base + pre - h;      // exclusive start of segment v
}

__global__ __launch_bounds__(256) void fill_kernel(
    const void* __restrict__ coords, const float* __restrict__ stats,
    const int* __restrict__ flag, unsigned* __restrict__ offsets,
    uint2* __restrict__ sorted)
{
  int isf = *flag;
  int gid = blockIdx.x*256 + threadIdx.x;
  int b = gid >> 15, n = gid & (NPTS-1);
  float4 st = ((const float4*)stats)[b];
  int idx[8]; float wts[8];
  compute_corners(coords, st, b, n, isf, idx, wts);
#pragma unroll
  for (int k = 0; k < 8; ++k){
    unsigned pos = atomicAdd(&offsets[(b << 15) + idx[k]], 1u);   // bumps to segment end
    sorted[pos] = make_uint2((unsigned)n, __float_as_uint(wts[k]));
  }
}

// PERSISTENT gather, SCATTERED assignment: 2048 blocks x 4 waves = 8192 waves
// (exactly 32 waves/CU). Wave w handles voxels v = ((w*32+k)*M) & (NVOX-1),
// k=0..31, M odd -> bijection mod 2^18 that scatters each wave's voxels across
// x, y, z AND batch.
__global__ __launch_bounds__(256) void gather_kernel(
    const uint2* __restrict__ sorted, const unsigned* __restrict__ offsets_end,
    const unsigned* __restrict__ hist, const bf16_t* __restrict__ feat_t,
    bf16_t* __restrict__ vox)
{
  const unsigned M = 162005u;          // odd -> bijective scatter mod 2^18
  int wid = blockIdx.x*4 + (threadIdx.x >> 6);
  int lane = threadIdx.x & 63;
  int g  = lane >> 3;                  // entry slot group
  int c8 = lane & 7;                   // 8 bf16 channels (16B) per lane

#pragma unroll 1
  for (int k = 0; k < 32; ++k){
    int v = (int)((((unsigned)wid << 5) | (unsigned)k) * M & (NVOX - 1u));
    unsigned end = offsets_end[v];
    unsigned cnt = hist[v];
    if (cnt == 0){
      if (g == 0){
        bf16x8 z;
#pragma unroll
        for (int j = 0; j < 8; ++j) z[j] = (bf16_t)0.f;
        *(bf16x8*)(vox + ((size_t)v << 6) + c8*8) = z;
      }
      continue;
    }
    int b = v >> 15;
    size_t fbase = ((size_t)b << 21);  // b*NPTS*64
    unsigned base = end - cnt;
    float acc[8] = {0.f,0.f,0.f,0.f,0.f,0.f,0.f,0.f};
    float cw = 0.f;
    // ---- full 64-entry blocks (unpredicated) ----
    for (; base + 64 <= end; base += 64){
      uint2 e[8];
#pragma unroll
      for (int d = 0; d < 8; ++d) e[d] = sorted[base + g + 8*d];
      bf16x8 f[8];
#pragma unroll
      for (int d = 0; d < 8; ++d)
        f[d] = *(const bf16x8*)(feat_t + fbase + ((size_t)e[d].x << 6) + c8*8);
#pragma unroll
      for (int d = 0; d < 8; ++d){
        float w = __uint_as_float(e[d].y);
#pragma unroll
        for (int j = 0; j < 8; ++j) acc[j] += w * (float)f[d][j];
        cw += w;
      }
    }
    // ---- 16-entry tail (predicated, depth 2) ----
    for (; base < end; base += 16){
      unsigned i0 = base + g, i1 = base + g + 8;
      uint2 e0 = (i0 < end) ? sorted[i0] : make_uint2(0u, 0u);
      uint2 e1 = (i1 < end) ? sorted[i1] : make_uint2(0u, 0u);
      bf16x8 f0 = *(const bf16x8*)(feat_t + fbase + ((size_t)e0.x << 6) + c8*8);
      bf16x8 f1 = *(const bf16x8*)(feat_t + fbase + ((size_t)e1.x << 6) + c8*8);
      float w0 = __uint_as_float(e0.y), w1 = __uint_as_float(e1.y);
#pragma unroll
      for (int j = 0; j < 8; ++j) acc[j] += w0 * (float)f0[j] + w1 * (float)f1[j];
      cw += w0 + w1;
    }
    // combine the 8 entry-slot groups (lanes differing in bits 3,4,5)
#pragma unroll
    for (int m = 8; m < 64; m <<= 1){
#pragma unroll
      for (int j = 0; j < 8; ++j) acc[j] += __shfl_xor(acc[j], m, 64);
      cw += __shfl_xor(cw, m, 64);
    }
    if (g == 0){
      float inv = 1.f / fmaxf(cw, 1e-8f);
      bf16x8 o;
#pragma unroll
      for (int j = 0; j < 8; ++j) o[j] = (bf16_t)(acc[j]*inv);
      *(bf16x8*)(vox + ((size_t)v << 6) + c8*8) = o;
    }
  }
}

// --------------------------------------------------------------- conv3d 3x3x3 + BN + LeakyReLU
// channels-last in/out [B*R3, 64]; tile: x fixed, y0..y0+3, z0..z0+15 (64 voxels / wg).
// Weights as per-wave REGISTER fragments from a fragment-major pack, 3-buffer
// rotation, ZERO barriers in the tap loop. Input tile XOR-swizzled 128B rows.
struct W8 { bf16x8 v[8]; };

__device__ __forceinline__ void load_wfrag(const bf16_t* __restrict__ wpack, int tap, int lane, W8& w){
#pragma unroll
  for (int f = 0; f < 8; ++f)
    w.v[f] = *(const bf16x8*)(wpack + (size_t)(tap*8 + f)*512 + lane*8);
}

__device__ __forceinline__ void tap_mfma(const bf16_t* lds_in, int rowidx, int quad, const W8& w,
                                         f32x4& a0, f32x4& a1, f32x4& a2, f32x4& a3){
  int swz = rowidx & 7;
#pragma unroll
  for (int ks = 0; ks < 2; ++ks){
    bf16x8 a = *(const bf16x8*)(lds_in + rowidx*64 + ((((ks<<2)|quad) ^ swz) << 3));
    a0 = __builtin_amdgcn_mfma_f32_16x16x32_bf16(a, w.v[ks*4+0], a0, 0, 0, 0);
    a1 = __builtin_amdgcn_mfma_f32_16x16x32_bf16(a, w.v[ks*4+1], a1, 0, 0, 0);
    a2 = __builtin_amdgcn_mfma_f32_16x16x32_bf16(a, w.v[ks*4+2], a2, 0, 0, 0);
    a3 = __builtin_amdgcn_mfma_f32_16x16x32_bf16(a, w.v[ks*4+3], a3, 0, 0, 0);
  }
}

__global__ __launch_bounds__(256, 3) void conv3d_kernel(
    const bf16_t* __restrict__ in, const bf16_t* __restrict__ wpack,   // frag-major [27][2][4][64][8]
    const float* __restrict__ scale, const float* __restrict__ shift,
    bf16_t* __restrict__ out)
{
  __shared__ bf16_t lds_in[324*64];      // 41,472 B, XOR-swizzled 128B rows
  int bid = blockIdx.x;
  int b  = bid >> 9;
  int x  = (bid >> 4) & 31;
  int y0 = ((bid >> 1) & 7) << 2;
  int z0 = (bid & 1) << 4;
  int t = threadIdx.x;
  for (int seg = t; seg < 324*8; seg += 256){
    int row = seg >> 3, part = seg & 7;
    int hx = row / 108, rem = row - hx*108;
    int hy = rem / 18,  hz = rem - hy*18;
    int gx = x + hx - 1, gy = y0 + hy - 1, gz = z0 + hz - 1;
    uint4 val = make_uint4(0u,0u,0u,0u);
    if ((unsigned)gx < 32u && (unsigned)gy < 32u && (unsigned)gz < 32u)
      val = *(const uint4*)(in + ((((size_t)(b*RR3 + ((gx<<10)+(gy<<5)+gz))) << 6) + part*8));
    *(uint4*)(lds_in + row*64 + ((part ^ (row & 7)) << 3)) = val;
  }
  int wave = t >> 6, lane = t & 63;
  int lrow = lane & 15, quad = lane >> 4;
  int rowbase = wave*18 + lrow;          // + dx*108 + dy*18 + dz per tap
  f32x4 acc0 = 0.f, acc1 = 0.f, acc2 = 0.f, acc3 = 0.f;

  W8 wA, wB, wC;
  load_wfrag(wpack, 0, lane, wA);        // prefetch tap 0
  load_wfrag(wpack, 1, lane, wB);        // prefetch tap 1
  __syncthreads();                       // only barrier: input tile ready

#pragma unroll
  for (int p = 0; p < 9; ++p){
    int t0 = 3*p, t1 = 3*p+1, t2 = 3*p+2;
    int n0 = (t0+2 < 27) ? t0+2 : 26;
    int n1 = (t1+2 < 27) ? t1+2 : 26;
    int n2 = (t2+2 < 27) ? t2+2 : 26;
    load_wfrag(wpack, n0, lane, wC);
    { int dx = t0/9, r9 = t0-dx*9, dy = r9/3, dz = r9-dy*3;
      tap_mfma(lds_in, rowbase + dx*108 + dy*18 + dz, quad, wA, acc0, acc1, acc2, acc3); }
    load_wfrag(wpack, n1, lane, wA);
    { int dx = t1/9, r9 = t1-dx*9, dy = r9/3, dz = r9-dy*3;
      tap_mfma(lds_in, rowbase + dx*108 + dy*18 + dz, quad, wB, acc0, acc1, acc2, acc3); }
    load_wfrag(wpack, n2, lane, wB);
    { int dx = t2/9, r9 = t2-dx*9, dy = r9/3, dz = r9-dy*3;
      tap_mfma(lds_in, rowbase + dx*108 + dy*18 + dz, quad, wC, acc0, acc1, acc2, acc3); }
  }

  f32x4 accs[4] = {acc0, acc1, acc2, acc3};
#pragma unroll
  for (int j = 0; j < 4; ++j){
    int co = j*16 + lrow;
    float sc = scale[co], sh = shift[co];
#pragma unroll
    for (int r = 0; r < 4; ++r){
      int zl = quad*4 + r;
      size_t o = (((size_t)(b*RR3 + ((x<<10) + ((y0+wave)<<5) + z0 + zl))) << 6) + co;
      float val = accs[j][r]*sc + sh;
      val = fmaxf(val, 0.1f*val);                    // LeakyReLU(0.1)
      out[o] = (bf16_t)val;
    }
  }
}

// --------------------------------------------------------------- devoxelize + point branch
// Point-branch MLP (64x64, K=64, 32 points/block) on MFMA: 2 p-tiles x 4
// o-tiles of 16x16, wave owns (ptile = w&1, otiles {2*(w>>1)+u}). Fragment
// mapping identical to conv3d. lw rows padded 64->72 elems: the old [o][64]
// layout made every wave's 8 distinct b128 reads alias the SAME 4-bank group
// (128B stride == 0 mod 32 banks) -> 8-way conflict, 5.9e7 conflict-cycles.
// Stride 144B == 4 banks -> conflict-free.
__global__ __launch_bounds__(256) void devox_kernel(
    const bf16_t* __restrict__ g,        // conv2 out [B*R3,64] channels-last
    const bf16_t* __restrict__ feat_t,   // [B*N,64] bf16 point-major
    const void* __restrict__ coords,
    const void* __restrict__ mlp_w,      // [64,64]
    const float* __restrict__ stats, const int* __restrict__ flag,
    const float* __restrict__ pscale, const float* __restrict__ pshift,
    void* __restrict__ out)              // [B,64,N]
{
  __shared__ bf16_t lf[32*72];           // feat tile [p][ci], padded
  __shared__ bf16_t lw[64*72];           // mlp_w [o][c], padded
  __shared__ float  lo[64*33];           // out tile [co][p]
  int t = threadIdx.x;
  int isf = *flag;
  int pb = blockIdx.x << 5;              // 32 points / block
  int b = pb >> 15, n0 = pb & (NPTS - 1);
  {
    int p = t >> 3, seg = t & 7;         // 256 threads == 32 points x 8 segs
    *(bf16x8*)(lf + p*72 + seg*8) =
        *(const bf16x8*)(feat_t + (((size_t)(b*NPTS + n0 + p)) << 6) + seg*8);
  }
  for (int i = t; i < 4096; i += 256){
    int o = i >> 6, c = i & 63;
    lw[o*72 + c] = (bf16_t)LD(mlp_w, i, isf);
  }
  __syncthreads();
  // ---- devoxelize gather (VALU), thread = (point p, channel-seg gseg) ----
  int p = t >> 3, gseg = t & 7;
  int n = n0 + p;
  float4 st = ((const float4*)stats)[b];
  int idx[8]; float wts[8];
  compute_corners(coords, st, b, n, isf, idx, wts);
  float dv[8] = {0,0,0,0,0,0,0,0};
#pragma unroll
  for (int k = 0; k < 8; ++k){
    bf16x8 gv = *(const bf16x8*)(g + (((size_t)(b*RR3 + idx[k])) << 6) + gseg*8);
    float w = wts[k];
#pragma unroll
    for (int j = 0; j < 8; ++j) dv[j] += w * (float)gv[j];
  }
#pragma unroll
  for (int j = 0; j < 8; ++j)
    lo[(gseg*8 + j)*33 + p] = dv[j];
  __syncthreads();
  // ---- point-branch MLP on MFMA ----
  int wave = t >> 6, lane = t & 63;
  int lrow = lane & 15, quad = lane >> 4;
  int ptile = wave & 1, og = wave >> 1;  // wave -> (ptile, otile pair)
  const bf16_t* arow = lf + (ptile*16 + lrow)*72;
  bf16x8 a0 = *(const bf16x8*)(arow + quad*8);
  bf16x8 a1 = *(const bf16x8*)(arow + 32 + quad*8);
#pragma unroll
  for (int u = 0; u < 2; ++u){
    int ot = og*2 + u;
    const bf16_t* brow = lw + (ot*16 + lrow)*72;
    bf16x8 b0 = *(const bf16x8*)(brow + quad*8);
    bf16x8 b1 = *(const bf16x8*)(brow + 32 + quad*8);
    f32x4 acc = 0.f;
    acc = __builtin_amdgcn_mfma_f32_16x16x32_bf16(a0, b0, acc, 0, 0, 0);
    acc = __builtin_amdgcn_mfma_f32_16x16x32_bf16(a1, b1, acc, 0, 0, 0);
    int o = ot*16 + lrow;
    float sc = pscale[o], sh = pshift[o];
#pragma unroll
    for (int r = 0; r < 4; ++r){
      int pl = ptile*16 + quad*4 + r;
      float q = fmaxf(acc[r]*sc + sh, 0.f);
      lo[o*33 + pl] += q;                // disjoint (o,pl) per wave: race-free
    }
  }
  __syncthreads();
  size_t obase = ((size_t)b << 21) + n0;
  if (isf){
    float* of = (float*)out;
    for (int i = t; i < 2048; i += 256){
      int co = i >> 5, pp = i & 31;
      of[obase + ((size_t)co << 15) + pp] = lo[co*33 + pp];
    }
  } else {
    bf16_t* oh = (bf16_t*)out;
    for (int i = t; i < 2048; i += 256){
      int co = i >> 5, pp = i & 31;
      oh[obase + ((size_t)co << 15) + pp] = (bf16_t)lo[co*33 + pp];
    }
  }
}

// --------------------------------------------------------------- coords passthrough
__global__ __launch_bounds__(256) void copy_coords_kernel(
    const void* __restrict__ coords, void* __restrict__ out, const int* __restrict__ flag){
  int i = blockIdx.x * 256 + threadIdx.x;
  if (i >= 786432) return;
  if (*flag) ((float*)out)[16777216 + i]  = ((const float*)coords)[i];
  else       ((bf16_t*)out)[16777216 + i] = ((const bf16_t*)coords)[i];
}

// --------------------------------------------------------------- param / weight prep
// fragment-major weight pack: dst[tap][ks][j][quad][lrow][e]
//   co = 16j + lrow, ci = ks*32 + quad*8 + e, lane = quad*16 + lrow
__global__ void prep_weights_kernel(const void* __restrict__ w1, const void* __restrict__ w2,
                                    const int* __restrict__ flag,
                                    bf16_t* __restrict__ wp1, bf16_t* __restrict__ wp2){
  int isf = *flag;
  int id = blockIdx.x * 256 + threadIdx.x;
  if (id >= 27*64*64) return;
  int off = id >> 12, co = (id >> 6) & 63, ci = id & 63;
  int src = (co*64 + ci)*27 + off;
  int j = co >> 4, lrow = co & 15;
  int ks = ci >> 5, quad = (ci >> 3) & 3, e = ci & 7;
  int dst = off*4096 + ks*2048 + j*512 + quad*128 + lrow*8 + e;
  wp1[dst] = (bf16_t)LD(w1, src, isf);
  wp2[dst] = (bf16_t)LD(w2, src, isf);
}

__global__ void prep_params_kernel(
    const void* c1b, const void* g1, const void* b1, const void* m1, const void* v1,
    const void* c2b, const void* g2, const void* b2, const void* m2, const void* v2,
    const void* pb_, const void* gp, const void* bp, const void* mp, const void* vp,
    const int* __restrict__ flag,
    float* __restrict__ P)   // [6][64]: s1, h1, s2, h2, sp, hp
{
  int isf = *flag;
  int c = threadIdx.x;
  if (c >= 64) return;
  float s1 = LD(g1,c,isf) / sqrtf(LD(v1,c,isf) + 1e-4f);
  P[c]       = s1;
  P[64 + c]  = (LD(c1b,c,isf) - LD(m1,c,isf))*s1 + LD(b1,c,isf);
  float s2 = LD(g2,c,isf) / sqrtf(LD(v2,c,isf) + 1e-4f);
  P[128 + c] = s2;
  P[192 + c] = (LD(c2b,c,isf) - LD(m2,c,isf))*s2 + LD(b2,c,isf);
  float sp = LD(gp,c,isf) / sqrtf(LD(vp,c,isf) + 1e-4f);
  P[256 + c] = sp;
  P[320 + c] = (LD(pb_,c,isf) - LD(mp,c,isf))*sp + LD(bp,c,isf);
}

// --------------------------------------------------------------- launch
extern "C" void kernel_launch(void* const* d_in, const int* in_sizes, int n_in,
                              void* d_out, int out_size, void* d_ws, size_t ws_size,
                              hipStream_t stream)
{
  const void* feat   = d_in[0];
  const void* coords = d_in[1];
  const void* c1w = d_in[2];
  const void* c1b = d_in[3];
  const void* g1  = d_in[4];
  const void* b1  = d_in[5];
  const void* m1  = d_in[6];
  const void* v1  = d_in[7];
  const void* c2w = d_in[8];
  const void* c2b = d_in[9];
  const void* g2  = d_in[10];
  const void* b2  = d_in[11];
  const void* m2  = d_in[12];
  const void* v2  = d_in[13];
  const void* mw  = d_in[14];
  const void* mb  = d_in[15];
  const void* gp  = d_in[16];
  const void* bp  = d_in[17];
  const void* mp  = d_in[18];
  const void* vp  = d_in[19];

  char* ws = (char*)d_ws;
  bf16_t*  feat_t  = (bf16_t*)(ws);                     // 33,554,432 B
  bf16_t*  vox     = (bf16_t*)(ws + 33554432);          // 33,554,432 B
  bf16_t*  c1out   = (bf16_t*)(ws + 67108864);          // 33,554,432 B
  bf16_t*  c2out   = vox;                               // vox dead after conv1
  uint2*   sorted  = (uint2*)(ws + 100663296);          // 16,777,216 B
  unsigned* hist   = (unsigned*)(ws + 117440512);       //  1,048,576 B
  unsigned* offs   = (unsigned*)(ws + 118489088);       //  1,048,576 B
  bf16_t*  wp1     = (bf16_t*)(ws + 119537664);         //    221,184 B
  bf16_t*  wp2     = (bf16_t*)(ws + 119758848);         //    221,184 B
  float*   P       = (float*)(ws + 119980032);          //      1,536 B
  float*   stats   = (float*)(ws + 119981568);          //        128 B
  int*     flag    = (int*)(ws + 119981696);            //        128 B
  unsigned* counter= (unsigned*)(ws + 119981824);       //        128 B
  float*   ssum    = (float*)(ws + 119981952);          //        128 B (8x4 f32)
  unsigned* smax   = (unsigned*)(ws + 119982080);       //        128 B

  hipMemsetAsync(flag, 0, 4, stream);
  hipMemsetAsync(hist, 0, 1048576, stream);
  hipMemsetAsync(counter, 0, 4, stream);
  hipMemsetAsync(ssum, 0, 256, stream);                 // ssum + smax
  detect_kernel<<<3072, 256, 0, stream>>>(coords, flag);
  prep_weights_kernel<<<432, 256, 0, stream>>>(c1w, c2w, flag, wp1, wp2);
  prep_params_kernel<<<1, 64, 0, stream>>>(c1b,g1,b1,m1,v1, c2b,g2,b2,m2,v2,
                                           mb,gp,bp,mp,vp, flag, P);
  stats_sum_kernel<<<256, 256, 0, stream>>>(coords, flag, ssum);
  stats_max_kernel<<<256, 256, 0, stream>>>(coords, flag, ssum, smax);
  stats_fin_kernel<<<1, 64, 0, stream>>>(ssum, smax, stats);
  transpose_kernel<<<4096, 256, 0, stream>>>(feat, flag, feat_t);
  hist_kernel<<<1024, 256, 0, stream>>>(coords, stats, flag, hist);
  offsets_kernel<<<1024, 256, 0, stream>>>(hist, offs, counter);
  fill_kernel<<<1024, 256, 0, stream>>>(coords, stats, flag, offs, sorted);
  gather_kernel<<<2048, 256, 0, stream>>>(sorted, offs, hist, feat_t, vox);
  conv3d_kernel<<<4096, 256, 0, stream>>>(vox,   wp1, P,       P + 64,  c1out);
  conv3d_kernel<<<4096, 256, 0, stream>>>(c1out, wp2, P + 128, P + 192, c2out);
  devox_kernel<<<8192, 256, 0, stream>>>(c2out, feat_t, coords, mw, stats, flag,
                                         P + 256, P + 320, d_out);
  copy_coords_kernel<<<3072, 256, 0, stream>>>(coords, d_out, flag);
}

// Round 8
// 722.175 us; speedup vs baseline: 1.3664x; 1.1104x over previous
//
#include <hip/hip_runtime.h>
#include <cstdint>
#include <cstddef>

#define NPTS  32768
#define NB    8
#define RR    32
#define RR3   32768
#define NVOX  (NB*RR3)          // 262144

typedef __bf16 bf16_t;
typedef __bf16 bf16x8 __attribute__((ext_vector_type(8)));
typedef __bf16 bf16x4 __attribute__((ext_vector_type(4)));
typedef float  f32x4  __attribute__((ext_vector_type(4)));
typedef float  f32x16 __attribute__((ext_vector_type(16)));

// adaptive load: input tensors may be fp32 or bf16 (detected at runtime)
__device__ __forceinline__ float LD(const void* p, size_t i, int isf){
  return isf ? ((const float*)p)[i] : (float)((const bf16_t*)p)[i];
}

// ---------------------------------------------------------------- reductions
__device__ __forceinline__ float wave_sum(float v){
#pragma unroll
  for (int o = 32; o > 0; o >>= 1) v += __shfl_down(v, o, 64);
  return v;
}
__device__ __forceinline__ float wave_max(float v){
#pragma unroll
  for (int o = 32; o > 0; o >>= 1) v = fmaxf(v, __shfl_down(v, o, 64));
  return v;
}

// --------------------------------------------------------------- dtype detect (parallel)
__global__ __launch_bounds__(256) void detect_kernel(const void* __restrict__ coords,
                                                     int* __restrict__ flag){
  int i = blockIdx.x*256 + threadIdx.x;
  const uint16_t* p = (const uint16_t*)coords;
  if ((p[i] & 0x7F80) == 0x7F80) atomicOr(flag, 1);   // 1 = fp32
}

// --------------------------------------------------------------- stats (3-phase parallel)
__global__ __launch_bounds__(256) void stats_sum_kernel(
    const void* __restrict__ coords, const int* __restrict__ flag, float* __restrict__ ssum){
  __shared__ float l[12];
  int isf = *flag;
  int b = blockIdx.x >> 5, blk = blockIdx.x & 31;     // 32 blocks per batch
  int t = threadIdx.x;
  size_t cb = ((size_t)b * 3) << 15;
  float sx = 0.f, sy = 0.f, sz = 0.f;
  int n0 = blk << 10;
  for (int n = n0 + t; n < n0 + 1024; n += 256){
    sx += LD(coords, cb + n, isf);
    sy += LD(coords, cb + NPTS + n, isf);
    sz += LD(coords, cb + 2*NPTS + n, isf);
  }
  sx = wave_sum(sx); sy = wave_sum(sy); sz = wave_sum(sz);
  int w = t >> 6;
  if ((t & 63) == 0){ l[w] = sx; l[4+w] = sy; l[8+w] = sz; }
  __syncthreads();
  if (t == 0){
    unsafeAtomicAdd(&ssum[b*4+0], l[0]+l[1]+l[2]+l[3]);
    unsafeAtomicAdd(&ssum[b*4+1], l[4]+l[5]+l[6]+l[7]);
    unsafeAtomicAdd(&ssum[b*4+2], l[8]+l[9]+l[10]+l[11]);
  }
}

__global__ __launch_bounds__(256) void stats_max_kernel(
    const void* __restrict__ coords, const int* __restrict__ flag,
    const float* __restrict__ ssum, unsigned* __restrict__ smax){
  __shared__ float l[4];
  int isf = *flag;
  int b = blockIdx.x >> 5, blk = blockIdx.x & 31;
  int t = threadIdx.x;
  size_t cb = ((size_t)b * 3) << 15;
  float mx = ssum[b*4+0] * (1.f/NPTS);
  float my = ssum[b*4+1] * (1.f/NPTS);
  float mz = ssum[b*4+2] * (1.f/NPTS);
  float mm = 0.f;
  int n0 = blk << 10;
  for (int n = n0 + t; n < n0 + 1024; n += 256){
    float cx = LD(coords, cb + n, isf) - mx;
    float cy = LD(coords, cb + NPTS + n, isf) - my;
    float cz = LD(coords, cb + 2*NPTS + n, isf) - mz;
    mm = fmaxf(mm, cx*cx + cy*cy + cz*cz);
  }
  mm = wave_max(mm);
  int w = t >> 6;
  if ((t & 63) == 0) l[w] = mm;
  __syncthreads();
  if (t == 0){
    float m = fmaxf(fmaxf(l[0], l[1]), fmaxf(l[2], l[3]));
    atomicMax(&smax[b], __float_as_uint(m));          // valid: m >= 0
  }
}

__global__ void stats_fin_kernel(const float* __restrict__ ssum,
                                 const unsigned* __restrict__ smax,
                                 float* __restrict__ stats){
  int b = threadIdx.x;
  if (b >= NB) return;
  float m = __uint_as_float(smax[b]);
  float inv = 32.f / (2.f * sqrtf(m) * (1.f + 1e-6f));
  float4 o;
  o.x = ssum[b*4+0] * (1.f/NPTS);
  o.y = ssum[b*4+1] * (1.f/NPTS);
  o.z = ssum[b*4+2] * (1.f/NPTS);
  o.w = inv;
  ((float4*)stats)[b] = o;
}

// --------------------------------------------------------------- corners
__device__ __forceinline__ void compute_corners(const void* __restrict__ coords, float4 st,
                                                int b, int n, int isf, int* idx, float* wts){
  size_t cbase = ((size_t)b * 3) << 15;
  float cx = LD(coords, cbase + n, isf)          - st.x;
  float cy = LD(coords, cbase + NPTS + n, isf)   - st.y;
  float cz = LD(coords, cbase + 2*NPTS + n, isf) - st.z;
  float vx = fminf(fmaxf(cx*st.w + 16.f, 0.f), 31.f);
  float vy = fminf(fmaxf(cy*st.w + 16.f, 0.f), 31.f);
  float vz = fminf(fmaxf(cz*st.w + 16.f, 0.f), 31.f);
  int lx = (int)vx, ly = (int)vy, lz = (int)vz;
  float fx = vx - (float)lx, fy = vy - (float)ly, fz = vz - (float)lz;
#pragma unroll
  for (int k = 0; k < 8; ++k){
    int dx = k >> 2, dy = (k >> 1) & 1, dz = k & 1;
    int xi = min(lx+dx, 31), yi = min(ly+dy, 31), zi = min(lz+dz, 31);
    idx[k] = (xi << 10) + (yi << 5) + zi;
    wts[k] = (dx ? fx : 1.f-fx) * (dy ? fy : 1.f-fy) * (dz ? fz : 1.f-fz);
  }
}

// --------------------------------------------------------------- transpose feat -> [B*N,64] bf16
__global__ __launch_bounds__(256) void transpose_kernel(
    const void* __restrict__ feat, const int* __restrict__ flag, bf16_t* __restrict__ feat_t)
{
  __shared__ float tile[64][65];
  int isf = *flag;
  int blk = blockIdx.x;            // 4096 = B * (N/64)
  int b = blk >> 9;
  int n0 = (blk & 511) << 6;
  int t = threadIdx.x, lane = t & 63, w = t >> 6;
  size_t base = ((size_t)b << 21); // b*64*N
  for (int ci = w; ci < 64; ci += 4)
    tile[ci][lane] = LD(feat, base + ((size_t)ci << 15) + n0 + lane, isf);
  __syncthreads();
  for (int i = t; i < 512; i += 256){
    int p = i >> 3, seg = i & 7;
    bf16x8 o;
#pragma unroll
    for (int e = 0; e < 8; ++e) o[e] = (bf16_t)tile[seg*8+e][p];
    *(bf16x8*)(feat_t + (((size_t)(b*NPTS + n0 + p)) << 6) + seg*8) = o;
  }
}

// --------------------------------------------------------------- voxelize: hist / offsets / fill / gather
__global__ __launch_bounds__(256) void hist_kernel(
    const void* __restrict__ coords, const float* __restrict__ stats,
    const int* __restrict__ flag, unsigned* __restrict__ hist)
{
  int isf = *flag;
  int gid = blockIdx.x*256 + threadIdx.x;
  int b = gid >> 15, n = gid & (NPTS-1);
  float4 st = ((const float4*)stats)[b];
  int idx[8]; float wts[8];
  compute_corners(coords, st, b, n, isf, idx, wts);
#pragma unroll
  for (int k = 0; k < 8; ++k) atomicAdd(&hist[(b << 15) + idx[k]], 1u);
}

__global__ __launch_bounds__(256) void offsets_kernel(
    const unsigned* __restrict__ hist, unsigned* __restrict__ offsets,
    unsigned* __restrict__ counter)
{
  int v = blockIdx.x*256 + threadIdx.x;
  int lane = threadIdx.x & 63;
  unsigned h = hist[v];
  unsigned pre = h;
#pragma unroll
  for (int o = 1; o < 64; o <<= 1){
    unsigned x = __shfl_up(pre, o, 64);
    if (lane >= o) pre += x;
  }
  unsigned total = __shfl(pre, 63, 64);
  unsigned base = 0;
  if (lane == 63) base = atomicAdd(counter, total);
  base = __shfl(base, 63, 64);
  offsets[v] = base + pre - h;      // exclusive start of segment v
}

__global__ __launch_bounds__(256) void fill_kernel(
    const void* __restrict__ coords, const float* __restrict__ stats,
    const int* __restrict__ flag, unsigned* __restrict__ offsets,
    uint2* __restrict__ sorted)
{
  int isf = *flag;
  int gid = blockIdx.x*256 + threadIdx.x;
  int b = gid >> 15, n = gid & (NPTS-1);
  float4 st = ((const float4*)stats)[b];
  int idx[8]; float wts[8];
  compute_corners(coords, st, b, n, isf, idx, wts);
#pragma unroll
  for (int k = 0; k < 8; ++k){
    unsigned pos = atomicAdd(&offsets[(b << 15) + idx[k]], 1u);   // bumps to segment end
    sorted[pos] = make_uint2((unsigned)n, __float_as_uint(wts[k]));
  }
}

// PERSISTENT gather, SCATTERED assignment: 2048 blocks x 4 waves = 8192 waves
// (exactly 32 waves/CU). Wave w handles voxels v = ((w*32+k)*M) & (NVOX-1),
// k=0..31, M odd -> bijection mod 2^18 that scatters each wave's voxels across
// x, y, z AND batch.
__global__ __launch_bounds__(256) void gather_kernel(
    const uint2* __restrict__ sorted, const unsigned* __restrict__ offsets_end,
    const unsigned* __restrict__ hist, const bf16_t* __restrict__ feat_t,
    bf16_t* __restrict__ vox)
{
  const unsigned M = 162005u;          // odd -> bijective scatter mod 2^18
  int wid = blockIdx.x*4 + (threadIdx.x >> 6);
  int lane = threadIdx.x & 63;
  int g  = lane >> 3;                  // entry slot group
  int c8 = lane & 7;                   // 8 bf16 channels (16B) per lane

#pragma unroll 1
  for (int k = 0; k < 32; ++k){
    int v = (int)((((unsigned)wid << 5) | (unsigned)k) * M & (NVOX - 1u));
    unsigned end = offsets_end[v];
    unsigned cnt = hist[v];
    if (cnt == 0){
      if (g == 0){
        bf16x8 z;
#pragma unroll
        for (int j = 0; j < 8; ++j) z[j] = (bf16_t)0.f;
        *(bf16x8*)(vox + ((size_t)v << 6) + c8*8) = z;
      }
      continue;
    }
    int b = v >> 15;
    size_t fbase = ((size_t)b << 21);  // b*NPTS*64
    unsigned base = end - cnt;
    float acc[8] = {0.f,0.f,0.f,0.f,0.f,0.f,0.f,0.f};
    float cw = 0.f;
    // ---- full 64-entry blocks (unpredicated) ----
    for (; base + 64 <= end; base += 64){
      uint2 e[8];
#pragma unroll
      for (int d = 0; d < 8; ++d) e[d] = sorted[base + g + 8*d];
      bf16x8 f[8];
#pragma unroll
      for (int d = 0; d < 8; ++d)
        f[d] = *(const bf16x8*)(feat_t + fbase + ((size_t)e[d].x << 6) + c8*8);
#pragma unroll
      for (int d = 0; d < 8; ++d){
        float w = __uint_as_float(e[d].y);
#pragma unroll
        for (int j = 0; j < 8; ++j) acc[j] += w * (float)f[d][j];
        cw += w;
      }
    }
    // ---- 16-entry tail (predicated, depth 2) ----
    for (; base < end; base += 16){
      unsigned i0 = base + g, i1 = base + g + 8;
      uint2 e0 = (i0 < end) ? sorted[i0] : make_uint2(0u, 0u);
      uint2 e1 = (i1 < end) ? sorted[i1] : make_uint2(0u, 0u);
      bf16x8 f0 = *(const bf16x8*)(feat_t + fbase + ((size_t)e0.x << 6) + c8*8);
      bf16x8 f1 = *(const bf16x8*)(feat_t + fbase + ((size_t)e1.x << 6) + c8*8);
      float w0 = __uint_as_float(e0.y), w1 = __uint_as_float(e1.y);
#pragma unroll
      for (int j = 0; j < 8; ++j) acc[j] += w0 * (float)f0[j] + w1 * (float)f1[j];
      cw += w0 + w1;
    }
    // combine the 8 entry-slot groups (lanes differing in bits 3,4,5)
#pragma unroll
    for (int m = 8; m < 64; m <<= 1){
#pragma unroll
      for (int j = 0; j < 8; ++j) acc[j] += __shfl_xor(acc[j], m, 64);
      cw += __shfl_xor(cw, m, 64);
    }
    if (g == 0){
      float inv = 1.f / fmaxf(cw, 1e-8f);
      bf16x8 o;
#pragma unroll
      for (int j = 0; j < 8; ++j) o[j] = (bf16_t)(acc[j]*inv);
      *(bf16x8*)(vox + ((size_t)v << 6) + c8*8) = o;
    }
  }
}

// --------------------------------------------------------------- conv3d 3x3x3 + BN + LeakyReLU
// channels-last in/out [B*R3, 64]; tile: x fixed, y0..y0+7, z0..z0+15 (128
// voxels / wg, wave = 2 y-rows = M=32). Round-7 PMC showed the 16x16 version
// was L1-BW-bound on weight fragment reloads (3.5 GB/dispatch ~= 64 B/cy/CU
// ~= 90us). Fix: mfma_f32_32x32x16 (2x FLOP per weight byte) + 2x output tile
// -> 1.77 GB/dispatch. Weights as per-wave REGISTER fragments from a 32x32
// fragment-major pack, 3-buffer rotation, ZERO barriers in the tap loop.
// Input tile XOR-swizzled 128B rows (proven conflict-free).
// 32x32x16 layouts (analog of verified 16x16x32; C/D HW-verified m74/m101):
//   A: row = lane&31, k = (lane>>5)*8 + e
//   B: col = lane&31, k = (lane>>5)*8 + e
//   D: col = lane&31, row = (reg&3) + 8*(reg>>2) + 4*(lane>>5)
struct W8 { bf16x8 v[8]; };

__device__ __forceinline__ void load_wfrag(const bf16_t* __restrict__ wpack, int tap, int lane, W8& w){
#pragma unroll
  for (int f = 0; f < 8; ++f)
    w.v[f] = *(const bf16x8*)(wpack + (size_t)(tap*8 + f)*512 + lane*8);
}

__device__ __forceinline__ void tap_mfma32(const bf16_t* lds_in, int rowidx, int khalf, const W8& w,
                                           f32x16& a0, f32x16& a1){
  int swz = rowidx & 7;
  const bf16_t* aptr = lds_in + rowidx*64;
#pragma unroll
  for (int q = 0; q < 4; ++q){
    bf16x8 a = *(const bf16x8*)(aptr + ((((q<<1)|khalf) ^ swz) << 3));
    a0 = __builtin_amdgcn_mfma_f32_32x32x16_bf16(a, w.v[q],   a0, 0, 0, 0);
    a1 = __builtin_amdgcn_mfma_f32_32x32x16_bf16(a, w.v[4+q], a1, 0, 0, 0);
  }
}

__global__ __launch_bounds__(256, 2) void conv3d_kernel(
    const bf16_t* __restrict__ in, const bf16_t* __restrict__ wpack,   // frag-major [27][nt2][q4][64][8]
    const float* __restrict__ scale, const float* __restrict__ shift,
    bf16_t* __restrict__ out)
{
  __shared__ bf16_t lds_in[540*64];      // 69,120 B, XOR-swizzled 128B rows
  int bid = blockIdx.x;                  // 2048 = 8b x 32x x 4yg x 2zg
  int b  = bid >> 8;
  int x  = (bid >> 3) & 31;
  int y0 = ((bid >> 1) & 3) << 3;
  int z0 = (bid & 1) << 4;
  int t = threadIdx.x;
  for (int seg = t; seg < 540*8; seg += 256){
    int row = seg >> 3, part = seg & 7;
    int hx = row / 180, rem = row - hx*180;
    int hy = rem / 18,  hz = rem - hy*18;
    int gx = x + hx - 1, gy = y0 + hy - 1, gz = z0 + hz - 1;
    uint4 val = make_uint4(0u,0u,0u,0u);
    if ((unsigned)gx < 32u && (unsigned)gy < 32u && (unsigned)gz < 32u)
      val = *(const uint4*)(in + ((((size_t)(b*RR3 + ((gx<<10)+(gy<<5)+gz))) << 6) + part*8));
    *(uint4*)(lds_in + row*64 + ((part ^ (row & 7)) << 3)) = val;
  }
  int wave = t >> 6, lane = t & 63;
  int lz    = lane & 15;
  int yloc  = (lane >> 4) & 1;
  int khalf = lane >> 5;
  int ybase = 2*wave + yloc;             // local y 0..7 (pre-halo)
  f32x16 acc0 = 0.f, acc1 = 0.f;

  W8 wA, wB, wC;
  load_wfrag(wpack, 0, lane, wA);        // prefetch tap 0
  load_wfrag(wpack, 1, lane, wB);        // prefetch tap 1
  __syncthreads();                       // only barrier: input tile ready

#pragma unroll
  for (int p = 0; p < 9; ++p){
    int t0 = 3*p, t1 = 3*p+1, t2 = 3*p+2;
    int n0 = (t0+2 < 27) ? t0+2 : 26;
    int n1 = (t1+2 < 27) ? t1+2 : 26;
    int n2 = (t2+2 < 27) ? t2+2 : 26;
    load_wfrag(wpack, n0, lane, wC);
    { int dx = t0/9, r9 = t0-dx*9, dy = r9/3, dz = r9-dy*3;
      tap_mfma32(lds_in, dx*180 + (ybase+dy)*18 + lz + dz, khalf, wA, acc0, acc1); }
    load_wfrag(wpack, n1, lane, wA);
    { int dx = t1/9, r9 = t1-dx*9, dy = r9/3, dz = r9-dy*3;
      tap_mfma32(lds_in, dx*180 + (ybase+dy)*18 + lz + dz, khalf, wB, acc0, acc1); }
    load_wfrag(wpack, n2, lane, wB);
    { int dx = t2/9, r9 = t2-dx*9, dy = r9/3, dz = r9-dy*3;
      tap_mfma32(lds_in, dx*180 + (ybase+dy)*18 + lz + dz, khalf, wC, acc0, acc1); }
  }

  f32x16 accs[2] = {acc0, acc1};
  int co_l = lane & 31;
#pragma unroll
  for (int nt = 0; nt < 2; ++nt){
    int co = nt*32 + co_l;
    float sc = scale[co], sh = shift[co];
#pragma unroll
    for (int r = 0; r < 16; ++r){
      int m = (r & 3) + ((r >> 2) << 3) + 4*khalf;   // voxel 0..31
      int z  = m & 15;
      int yl = m >> 4;
      int y  = y0 + 2*wave + yl;
      size_t o = (((size_t)(b*RR3 + ((x<<10) + (y<<5) + z0 + z))) << 6) + co;
      float val = accs[nt][r]*sc + sh;
      val = fmaxf(val, 0.1f*val);                    // LeakyReLU(0.1)
      out[o] = (bf16_t)val;
    }
  }
}

// --------------------------------------------------------------- devoxelize + point branch
// Point-branch MLP (64x64, K=64, 32 points/block) on MFMA: 2 p-tiles x 4
// o-tiles of 16x16, wave owns (ptile = w&1, otiles {2*(w>>1)+u}). lw rows
// padded 64->72 elems (stride 144B == 4 banks -> conflict-free).
__global__ __launch_bounds__(256) void devox_kernel(
    const bf16_t* __restrict__ g,        // conv2 out [B*R3,64] channels-last
    const bf16_t* __restrict__ feat_t,   // [B*N,64] bf16 point-major
    const void* __restrict__ coords,
    const void* __restrict__ mlp_w,      // [64,64]
    const float* __restrict__ stats, const int* __restrict__ flag,
    const float* __restrict__ pscale, const float* __restrict__ pshift,
    void* __restrict__ out)              // [B,64,N]
{
  __shared__ bf16_t lf[32*72];           // feat tile [p][ci], padded
  __shared__ bf16_t lw[64*72];           // mlp_w [o][c], padded
  __shared__ float  lo[64*33];           // out tile [co][p]
  int t = threadIdx.x;
  int isf = *flag;
  int pb = blockIdx.x << 5;              // 32 points / block
  int b = pb >> 15, n0 = pb & (NPTS - 1);
  {
    int p = t >> 3, seg = t & 7;         // 256 threads == 32 points x 8 segs
    *(bf16x8*)(lf + p*72 + seg*8) =
        *(const bf16x8*)(feat_t + (((size_t)(b*NPTS + n0 + p)) << 6) + seg*8);
  }
  for (int i = t; i < 4096; i += 256){
    int o = i >> 6, c = i & 63;
    lw[o*72 + c] = (bf16_t)LD(mlp_w, i, isf);
  }
  __syncthreads();
  // ---- devoxelize gather (VALU), thread = (point p, channel-seg gseg) ----
  int p = t >> 3, gseg = t & 7;
  int n = n0 + p;
  float4 st = ((const float4*)stats)[b];
  int idx[8]; float wts[8];
  compute_corners(coords, st, b, n, isf, idx, wts);
  float dv[8] = {0,0,0,0,0,0,0,0};
#pragma unroll
  for (int k = 0; k < 8; ++k){
    bf16x8 gv = *(const bf16x8*)(g + (((size_t)(b*RR3 + idx[k])) << 6) + gseg*8);
    float w = wts[k];
#pragma unroll
    for (int j = 0; j < 8; ++j) dv[j] += w * (float)gv[j];
  }
#pragma unroll
  for (int j = 0; j < 8; ++j)
    lo[(gseg*8 + j)*33 + p] = dv[j];
  __syncthreads();
  // ---- point-branch MLP on MFMA ----
  int wave = t >> 6, lane = t & 63;
  int lrow = lane & 15, quad = lane >> 4;
  int ptile = wave & 1, og = wave >> 1;  // wave -> (ptile, otile pair)
  const bf16_t* arow = lf + (ptile*16 + lrow)*72;
  bf16x8 a0 = *(const bf16x8*)(arow + quad*8);
  bf16x8 a1 = *(const bf16x8*)(arow + 32 + quad*8);
#pragma unroll
  for (int u = 0; u < 2; ++u){
    int ot = og*2 + u;
    const bf16_t* brow = lw + (ot*16 + lrow)*72;
    bf16x8 b0 = *(const bf16x8*)(brow + quad*8);
    bf16x8 b1 = *(const bf16x8*)(brow + 32 + quad*8);
    f32x4 acc = 0.f;
    acc = __builtin_amdgcn_mfma_f32_16x16x32_bf16(a0, b0, acc, 0, 0, 0);
    acc = __builtin_amdgcn_mfma_f32_16x16x32_bf16(a1, b1, acc, 0, 0, 0);
    int o = ot*16 + lrow;
    float sc = pscale[o], sh = pshift[o];
#pragma unroll
    for (int r = 0; r < 4; ++r){
      int pl = ptile*16 + quad*4 + r;
      float q = fmaxf(acc[r]*sc + sh, 0.f);
      lo[o*33 + pl] += q;                // disjoint (o,pl) per wave: race-free
    }
  }
  __syncthreads();
  size_t obase = ((size_t)b << 21) + n0;
  if (isf){
    float* of = (float*)out;
    for (int i = t; i < 2048; i += 256){
      int co = i >> 5, pp = i & 31;
      of[obase + ((size_t)co << 15) + pp] = lo[co*33 + pp];
    }
  } else {
    bf16_t* oh = (bf16_t*)out;
    for (int i = t; i < 2048; i += 256){
      int co = i >> 5, pp = i & 31;
      oh[obase + ((size_t)co << 15) + pp] = (bf16_t)lo[co*33 + pp];
    }
  }
}

// --------------------------------------------------------------- coords passthrough
__global__ __launch_bounds__(256) void copy_coords_kernel(
    const void* __restrict__ coords, void* __restrict__ out, const int* __restrict__ flag){
  int i = blockIdx.x * 256 + threadIdx.x;
  if (i >= 786432) return;
  if (*flag) ((float*)out)[16777216 + i]  = ((const float*)coords)[i];
  else       ((bf16_t*)out)[16777216 + i] = ((const bf16_t*)coords)[i];
}

// --------------------------------------------------------------- param / weight prep
// fragment-major 32x32 weight pack: dst[tap][ntile][q][lane][e]
//   co = ntile*32 + lcol, ci = q*16 + khalf*8 + e, lane = khalf*32 + lcol
__global__ void prep_weights_kernel(const void* __restrict__ w1, const void* __restrict__ w2,
                                    const int* __restrict__ flag,
                                    bf16_t* __restrict__ wp1, bf16_t* __restrict__ wp2){
  int isf = *flag;
  int id = blockIdx.x * 256 + threadIdx.x;
  if (id >= 27*64*64) return;
  int off = id >> 12, co = (id >> 6) & 63, ci = id & 63;
  int src = (co*64 + ci)*27 + off;
  int ntile = co >> 5, lcol = co & 31;
  int q = ci >> 4, khalf = (ci >> 3) & 1, e = ci & 7;
  int dst = off*4096 + ntile*2048 + q*512 + (khalf*32 + lcol)*8 + e;
  wp1[dst] = (bf16_t)LD(w1, src, isf);
  wp2[dst] = (bf16_t)LD(w2, src, isf);
}

__global__ void prep_params_kernel(
    const void* c1b, const void* g1, const void* b1, const void* m1, const void* v1,
    const void* c2b, const void* g2, const void* b2, const void* m2, const void* v2,
    const void* pb_, const void* gp, const void* bp, const void* mp, const void* vp,
    const int* __restrict__ flag,
    float* __restrict__ P)   // [6][64]: s1, h1, s2, h2, sp, hp
{
  int isf = *flag;
  int c = threadIdx.x;
  if (c >= 64) return;
  float s1 = LD(g1,c,isf) / sqrtf(LD(v1,c,isf) + 1e-4f);
  P[c]       = s1;
  P[64 + c]  = (LD(c1b,c,isf) - LD(m1,c,isf))*s1 + LD(b1,c,isf);
  float s2 = LD(g2,c,isf) / sqrtf(LD(v2,c,isf) + 1e-4f);
  P[128 + c] = s2;
  P[192 + c] = (LD(c2b,c,isf) - LD(m2,c,isf))*s2 + LD(b2,c,isf);
  float sp = LD(gp,c,isf) / sqrtf(LD(vp,c,isf) + 1e-4f);
  P[256 + c] = sp;
  P[320 + c] = (LD(pb_,c,isf) - LD(mp,c,isf))*sp + LD(bp,c,isf);
}

// --------------------------------------------------------------- launch
extern "C" void kernel_launch(void* const* d_in, const int* in_sizes, int n_in,
                              void* d_out, int out_size, void* d_ws, size_t ws_size,
                              hipStream_t stream)
{
  const void* feat   = d_in[0];
  const void* coords = d_in[1];
  const void* c1w = d_in[2];
  const void* c1b = d_in[3];
  const void* g1  = d_in[4];
  const void* b1  = d_in[5];
  const void* m1  = d_in[6];
  const void* v1  = d_in[7];
  const void* c2w = d_in[8];
  const void* c2b = d_in[9];
  const void* g2  = d_in[10];
  const void* b2  = d_in[11];
  const void* m2  = d_in[12];
  const void* v2  = d_in[13];
  const void* mw  = d_in[14];
  const void* mb  = d_in[15];
  const void* gp  = d_in[16];
  const void* bp  = d_in[17];
  const void* mp  = d_in[18];
  const void* vp  = d_in[19];

  char* ws = (char*)d_ws;
  bf16_t*  feat_t  = (bf16_t*)(ws);                     // 33,554,432 B
  bf16_t*  vox     = (bf16_t*)(ws + 33554432);          // 33,554,432 B
  bf16_t*  c1out   = (bf16_t*)(ws + 67108864);          // 33,554,432 B
  bf16_t*  c2out   = vox;                               // vox dead after conv1
  uint2*   sorted  = (uint2*)(ws + 100663296);          // 16,777,216 B
  unsigned* hist   = (unsigned*)(ws + 117440512);       //  1,048,576 B
  unsigned* offs   = (unsigned*)(ws + 118489088);       //  1,048,576 B
  bf16_t*  wp1     = (bf16_t*)(ws + 119537664);         //    221,184 B
  bf16_t*  wp2     = (bf16_t*)(ws + 119758848);         //    221,184 B
  float*   P       = (float*)(ws + 119980032);          //      1,536 B
  float*   stats   = (float*)(ws + 119981568);          //        128 B
  int*     flag    = (int*)(ws + 119981696);            //        128 B
  unsigned* counter= (unsigned*)(ws + 119981824);       //        128 B
  float*   ssum    = (float*)(ws + 119981952);          //        128 B (8x4 f32)
  unsigned* smax   = (unsigned*)(ws + 119982080);       //        128 B

  hipMemsetAsync(flag, 0, 4, stream);
  hipMemsetAsync(hist, 0, 1048576, stream);
  hipMemsetAsync(counter, 0, 4, stream);
  hipMemsetAsync(ssum, 0, 256, stream);                 // ssum + smax
  detect_kernel<<<3072, 256, 0, stream>>>(coords, flag);
  prep_weights_kernel<<<432, 256, 0, stream>>>(c1w, c2w, flag, wp1, wp2);
  prep_params_kernel<<<1, 64, 0, stream>>>(c1b,g1,b1,m1,v1, c2b,g2,b2,m2,v2,
                                           mb,gp,bp,mp,vp, flag, P);
  stats_sum_kernel<<<256, 256, 0, stream>>>(coords, flag, ssum);
  stats_max_kernel<<<256, 256, 0, stream>>>(coords, flag, ssum, smax);
  stats_fin_kernel<<<1, 64, 0, stream>>>(ssum, smax, stats);
  transpose_kernel<<<4096, 256, 0, stream>>>(feat, flag, feat_t);
  hist_kernel<<<1024, 256, 0, stream>>>(coords, stats, flag, hist);
  offsets_kernel<<<1024, 256, 0, stream>>>(hist, offs, counter);
  fill_kernel<<<1024, 256, 0, stream>>>(coords, stats, flag, offs, sorted);
  gather_kernel<<<2048, 256, 0, stream>>>(sorted, offs, hist, feat_t, vox);
  conv3d_kernel<<<2048, 256, 0, stream>>>(vox,   wp1, P,       P + 64,  c1out);
  conv3d_kernel<<<2048, 256, 0, stream>>>(c1out, wp2, P + 128, P + 192, c2out);
  devox_kernel<<<8192, 256, 0, stream>>>(c2out, feat_t, coords, mw, stats, flag,
                                         P + 256, P + 320, d_out);
  copy_coords_kernel<<<3072, 256, 0, stream>>>(coords, d_out, flag);
}

// Round 9
// 712.254 us; speedup vs baseline: 1.3854x; 1.0139x over previous
//
#include <hip/hip_runtime.h>
#include <cstdint>
#include <cstddef>

#define NPTS  32768
#define NB    8
#define RR    32
#define RR3   32768
#define NVOX  (NB*RR3)          // 262144

typedef __bf16 bf16_t;
typedef __bf16 bf16x8 __attribute__((ext_vector_type(8)));
typedef __bf16 bf16x4 __attribute__((ext_vector_type(4)));
typedef float  f32x4  __attribute__((ext_vector_type(4)));
typedef float  f32x16 __attribute__((ext_vector_type(16)));

// adaptive load: input tensors may be fp32 or bf16 (detected at runtime)
__device__ __forceinline__ float LD(const void* p, size_t i, int isf){
  return isf ? ((const float*)p)[i] : (float)((const bf16_t*)p)[i];
}

// ---------------------------------------------------------------- reductions
__device__ __forceinline__ float wave_sum(float v){
#pragma unroll
  for (int o = 32; o > 0; o >>= 1) v += __shfl_down(v, o, 64);
  return v;
}
__device__ __forceinline__ float wave_max(float v){
#pragma unroll
  for (int o = 32; o > 0; o >>= 1) v = fmaxf(v, __shfl_down(v, o, 64));
  return v;
}

// --------------------------------------------------------------- dtype detect (parallel)
__global__ __launch_bounds__(256) void detect_kernel(const void* __restrict__ coords,
                                                     int* __restrict__ flag){
  int i = blockIdx.x*256 + threadIdx.x;
  const uint16_t* p = (const uint16_t*)coords;
  if ((p[i] & 0x7F80) == 0x7F80) atomicOr(flag, 1);   // 1 = fp32
}

// --------------------------------------------------------------- stats (3-phase parallel)
__global__ __launch_bounds__(256) void stats_sum_kernel(
    const void* __restrict__ coords, const int* __restrict__ flag, float* __restrict__ ssum){
  __shared__ float l[12];
  int isf = *flag;
  int b = blockIdx.x >> 5, blk = blockIdx.x & 31;     // 32 blocks per batch
  int t = threadIdx.x;
  size_t cb = ((size_t)b * 3) << 15;
  float sx = 0.f, sy = 0.f, sz = 0.f;
  int n0 = blk << 10;
  for (int n = n0 + t; n < n0 + 1024; n += 256){
    sx += LD(coords, cb + n, isf);
    sy += LD(coords, cb + NPTS + n, isf);
    sz += LD(coords, cb + 2*NPTS + n, isf);
  }
  sx = wave_sum(sx); sy = wave_sum(sy); sz = wave_sum(sz);
  int w = t >> 6;
  if ((t & 63) == 0){ l[w] = sx; l[4+w] = sy; l[8+w] = sz; }
  __syncthreads();
  if (t == 0){
    unsafeAtomicAdd(&ssum[b*4+0], l[0]+l[1]+l[2]+l[3]);
    unsafeAtomicAdd(&ssum[b*4+1], l[4]+l[5]+l[6]+l[7]);
    unsafeAtomicAdd(&ssum[b*4+2], l[8]+l[9]+l[10]+l[11]);
  }
}

__global__ __launch_bounds__(256) void stats_max_kernel(
    const void* __restrict__ coords, const int* __restrict__ flag,
    const float* __restrict__ ssum, unsigned* __restrict__ smax){
  __shared__ float l[4];
  int isf = *flag;
  int b = blockIdx.x >> 5, blk = blockIdx.x & 31;
  int t = threadIdx.x;
  size_t cb = ((size_t)b * 3) << 15;
  float mx = ssum[b*4+0] * (1.f/NPTS);
  float my = ssum[b*4+1] * (1.f/NPTS);
  float mz = ssum[b*4+2] * (1.f/NPTS);
  float mm = 0.f;
  int n0 = blk << 10;
  for (int n = n0 + t; n < n0 + 1024; n += 256){
    float cx = LD(coords, cb + n, isf) - mx;
    float cy = LD(coords, cb + NPTS + n, isf) - my;
    float cz = LD(coords, cb + 2*NPTS + n, isf) - mz;
    mm = fmaxf(mm, cx*cx + cy*cy + cz*cz);
  }
  mm = wave_max(mm);
  int w = t >> 6;
  if ((t & 63) == 0) l[w] = mm;
  __syncthreads();
  if (t == 0){
    float m = fmaxf(fmaxf(l[0], l[1]), fmaxf(l[2], l[3]));
    atomicMax(&smax[b], __float_as_uint(m));          // valid: m >= 0
  }
}

__global__ void stats_fin_kernel(const float* __restrict__ ssum,
                                 const unsigned* __restrict__ smax,
                                 float* __restrict__ stats){
  int b = threadIdx.x;
  if (b >= NB) return;
  float m = __uint_as_float(smax[b]);
  float inv = 32.f / (2.f * sqrtf(m) * (1.f + 1e-6f));
  float4 o;
  o.x = ssum[b*4+0] * (1.f/NPTS);
  o.y = ssum[b*4+1] * (1.f/NPTS);
  o.z = ssum[b*4+2] * (1.f/NPTS);
  o.w = inv;
  ((float4*)stats)[b] = o;
}

// --------------------------------------------------------------- corners
__device__ __forceinline__ void compute_corners(const void* __restrict__ coords, float4 st,
                                                int b, int n, int isf, int* idx, float* wts){
  size_t cbase = ((size_t)b * 3) << 15;
  float cx = LD(coords, cbase + n, isf)          - st.x;
  float cy = LD(coords, cbase + NPTS + n, isf)   - st.y;
  float cz = LD(coords, cbase + 2*NPTS + n, isf) - st.z;
  float vx = fminf(fmaxf(cx*st.w + 16.f, 0.f), 31.f);
  float vy = fminf(fmaxf(cy*st.w + 16.f, 0.f), 31.f);
  float vz = fminf(fmaxf(cz*st.w + 16.f, 0.f), 31.f);
  int lx = (int)vx, ly = (int)vy, lz = (int)vz;
  float fx = vx - (float)lx, fy = vy - (float)ly, fz = vz - (float)lz;
#pragma unroll
  for (int k = 0; k < 8; ++k){
    int dx = k >> 2, dy = (k >> 1) & 1, dz = k & 1;
    int xi = min(lx+dx, 31), yi = min(ly+dy, 31), zi = min(lz+dz, 31);
    idx[k] = (xi << 10) + (yi << 5) + zi;
    wts[k] = (dx ? fx : 1.f-fx) * (dy ? fy : 1.f-fy) * (dz ? fz : 1.f-fz);
  }
}

// --------------------------------------------------------------- transpose feat -> [B*N,64] bf16
__global__ __launch_bounds__(256) void transpose_kernel(
    const void* __restrict__ feat, const int* __restrict__ flag, bf16_t* __restrict__ feat_t)
{
  __shared__ float tile[64][65];
  int isf = *flag;
  int blk = blockIdx.x;            // 4096 = B * (N/64)
  int b = blk >> 9;
  int n0 = (blk & 511) << 6;
  int t = threadIdx.x, lane = t & 63, w = t >> 6;
  size_t base = ((size_t)b << 21); // b*64*N
  for (int ci = w; ci < 64; ci += 4)
    tile[ci][lane] = LD(feat, base + ((size_t)ci << 15) + n0 + lane, isf);
  __syncthreads();
  for (int i = t; i < 512; i += 256){
    int p = i >> 3, seg = i & 7;
    bf16x8 o;
#pragma unroll
    for (int e = 0; e < 8; ++e) o[e] = (bf16_t)tile[seg*8+e][p];
    *(bf16x8*)(feat_t + (((size_t)(b*NPTS + n0 + p)) << 6) + seg*8) = o;
  }
}

// --------------------------------------------------------------- voxelize: hist / offsets / fill / gather
__global__ __launch_bounds__(256) void hist_kernel(
    const void* __restrict__ coords, const float* __restrict__ stats,
    const int* __restrict__ flag, unsigned* __restrict__ hist)
{
  int isf = *flag;
  int gid = blockIdx.x*256 + threadIdx.x;
  int b = gid >> 15, n = gid & (NPTS-1);
  float4 st = ((const float4*)stats)[b];
  int idx[8]; float wts[8];
  compute_corners(coords, st, b, n, isf, idx, wts);
#pragma unroll
  for (int k = 0; k < 8; ++k) atomicAdd(&hist[(b << 15) + idx[k]], 1u);
}

__global__ __launch_bounds__(256) void offsets_kernel(
    const unsigned* __restrict__ hist, unsigned* __restrict__ offsets,
    unsigned* __restrict__ counter)
{
  int v = blockIdx.x*256 + threadIdx.x;
  int lane = threadIdx.x & 63;
  unsigned h = hist[v];
  unsigned pre = h;
#pragma unroll
  for (int o = 1; o < 64; o <<= 1){
    unsigned x = __shfl_up(pre, o, 64);
    if (lane >= o) pre += x;
  }
  unsigned total = __shfl(pre, 63, 64);
  unsigned base = 0;
  if (lane == 63) base = atomicAdd(counter, total);
  base = __shfl(base, 63, 64);
  offsets[v] = base + pre - h;      // exclusive start of segment v
}

// XCD-local slab fill: round-8 PMC showed fill was HBM-scatter-write-bound
// (WRITE_SIZE 115 MB for 16.8 MB of useful entries ~= 7x line amplification:
// a segment's entries arrive from random blocks on all 8 non-coherent XCD L2s,
// so the same 64B line is partially written back many times). Fix: block bid
// handles ONLY corners with voxel-x & 7 == bid & 7. With the bid%8 -> XCD
// round-robin mapping, every sorted line has a single writer XCD whose L2
// (4MB >> 2.1MB active slice) assembles it fully -> ~1 writeback per line.
// Each block scans 8x the points (coords re-read 8x = 18MB, VALU ~3% - free).
// Every (point,corner) is handled exactly once regardless of the XCD mapping.
__global__ __launch_bounds__(256) void fill_kernel(
    const void* __restrict__ coords, const float* __restrict__ stats,
    const int* __restrict__ flag, unsigned* __restrict__ offsets,
    uint2* __restrict__ sorted)
{
  int isf = *flag;
  int slab  = blockIdx.x & 7;          // voxel-x mod 8 handled by this block
  int chunk = blockIdx.x >> 3;         // 128 chunks x 2048 points
  int p0 = (chunk << 11) + threadIdx.x;
#pragma unroll 1
  for (int it = 0; it < 8; ++it){
    int gid = p0 + (it << 8);
    int b = gid >> 15, n = gid & (NPTS-1);
    float4 st = ((const float4*)stats)[b];
    int idx[8]; float wts[8];
    compute_corners(coords, st, b, n, isf, idx, wts);
#pragma unroll
    for (int k = 0; k < 8; ++k){
      if (((idx[k] >> 10) & 7) == slab){
        unsigned pos = atomicAdd(&offsets[(b << 15) + idx[k]], 1u);  // bump to segment end
        sorted[pos] = make_uint2((unsigned)n, __float_as_uint(wts[k]));
      }
    }
  }
}

// PERSISTENT gather, SCATTERED assignment: 2048 blocks x 4 waves = 8192 waves
// (exactly 32 waves/CU). Wave w handles voxels v = ((w*32+k)*M) & (NVOX-1),
// k=0..31, M odd -> bijection mod 2^18 that scatters each wave's voxels across
// x, y, z AND batch.
__global__ __launch_bounds__(256) void gather_kernel(
    const uint2* __restrict__ sorted, const unsigned* __restrict__ offsets_end,
    const unsigned* __restrict__ hist, const bf16_t* __restrict__ feat_t,
    bf16_t* __restrict__ vox)
{
  const unsigned M = 162005u;          // odd -> bijective scatter mod 2^18
  int wid = blockIdx.x*4 + (threadIdx.x >> 6);
  int lane = threadIdx.x & 63;
  int g  = lane >> 3;                  // entry slot group
  int c8 = lane & 7;                   // 8 bf16 channels (16B) per lane

#pragma unroll 1
  for (int k = 0; k < 32; ++k){
    int v = (int)((((unsigned)wid << 5) | (unsigned)k) * M & (NVOX - 1u));
    unsigned end = offsets_end[v];
    unsigned cnt = hist[v];
    if (cnt == 0){
      if (g == 0){
        bf16x8 z;
#pragma unroll
        for (int j = 0; j < 8; ++j) z[j] = (bf16_t)0.f;
        *(bf16x8*)(vox + ((size_t)v << 6) + c8*8) = z;
      }
      continue;
    }
    int b = v >> 15;
    size_t fbase = ((size_t)b << 21);  // b*NPTS*64
    unsigned base = end - cnt;
    float acc[8] = {0.f,0.f,0.f,0.f,0.f,0.f,0.f,0.f};
    float cw = 0.f;
    // ---- full 64-entry blocks (unpredicated) ----
    for (; base + 64 <= end; base += 64){
      uint2 e[8];
#pragma unroll
      for (int d = 0; d < 8; ++d) e[d] = sorted[base + g + 8*d];
      bf16x8 f[8];
#pragma unroll
      for (int d = 0; d < 8; ++d)
        f[d] = *(const bf16x8*)(feat_t + fbase + ((size_t)e[d].x << 6) + c8*8);
#pragma unroll
      for (int d = 0; d < 8; ++d){
        float w = __uint_as_float(e[d].y);
#pragma unroll
        for (int j = 0; j < 8; ++j) acc[j] += w * (float)f[d][j];
        cw += w;
      }
    }
    // ---- 16-entry tail (predicated, depth 2) ----
    for (; base < end; base += 16){
      unsigned i0 = base + g, i1 = base + g + 8;
      uint2 e0 = (i0 < end) ? sorted[i0] : make_uint2(0u, 0u);
      uint2 e1 = (i1 < end) ? sorted[i1] : make_uint2(0u, 0u);
      bf16x8 f0 = *(const bf16x8*)(feat_t + fbase + ((size_t)e0.x << 6) + c8*8);
      bf16x8 f1 = *(const bf16x8*)(feat_t + fbase + ((size_t)e1.x << 6) + c8*8);
      float w0 = __uint_as_float(e0.y), w1 = __uint_as_float(e1.y);
#pragma unroll
      for (int j = 0; j < 8; ++j) acc[j] += w0 * (float)f0[j] + w1 * (float)f1[j];
      cw += w0 + w1;
    }
    // combine the 8 entry-slot groups (lanes differing in bits 3,4,5)
#pragma unroll
    for (int m = 8; m < 64; m <<= 1){
#pragma unroll
      for (int j = 0; j < 8; ++j) acc[j] += __shfl_xor(acc[j], m, 64);
      cw += __shfl_xor(cw, m, 64);
    }
    if (g == 0){
      float inv = 1.f / fmaxf(cw, 1e-8f);
      bf16x8 o;
#pragma unroll
      for (int j = 0; j < 8; ++j) o[j] = (bf16_t)(acc[j]*inv);
      *(bf16x8*)(vox + ((size_t)v << 6) + c8*8) = o;
    }
  }
}

// --------------------------------------------------------------- conv3d 3x3x3 + BN + LeakyReLU
// channels-last in/out [B*R3, 64]; tile: x fixed, y0..y0+7, z0..z0+15 (128
// voxels / wg, wave = 2 y-rows = M=32). mfma_f32_32x32x16 (2x FLOP per weight
// byte vs 16x16) + 128-voxel tile -> 1.77 GB/dispatch weight traffic. Weights
// as per-wave REGISTER fragments from a 32x32 fragment-major pack, 3-buffer
// rotation, ZERO barriers in the tap loop. Input tile XOR-swizzled 128B rows.
//   A: row = lane&31, k = (lane>>5)*8 + e
//   B: col = lane&31, k = (lane>>5)*8 + e
//   D: col = lane&31, row = (reg&3) + 8*(reg>>2) + 4*(lane>>5)
struct W8 { bf16x8 v[8]; };

__device__ __forceinline__ void load_wfrag(const bf16_t* __restrict__ wpack, int tap, int lane, W8& w){
#pragma unroll
  for (int f = 0; f < 8; ++f)
    w.v[f] = *(const bf16x8*)(wpack + (size_t)(tap*8 + f)*512 + lane*8);
}

__device__ __forceinline__ void tap_mfma32(const bf16_t* lds_in, int rowidx, int khalf, const W8& w,
                                           f32x16& a0, f32x16& a1){
  int swz = rowidx & 7;
  const bf16_t* aptr = lds_in + rowidx*64;
#pragma unroll
  for (int q = 0; q < 4; ++q){
    bf16x8 a = *(const bf16x8*)(aptr + ((((q<<1)|khalf) ^ swz) << 3));
    a0 = __builtin_amdgcn_mfma_f32_32x32x16_bf16(a, w.v[q],   a0, 0, 0, 0);
    a1 = __builtin_amdgcn_mfma_f32_32x32x16_bf16(a, w.v[4+q], a1, 0, 0, 0);
  }
}

__global__ __launch_bounds__(256, 2) void conv3d_kernel(
    const bf16_t* __restrict__ in, const bf16_t* __restrict__ wpack,   // frag-major [27][nt2][q4][64][8]
    const float* __restrict__ scale, const float* __restrict__ shift,
    bf16_t* __restrict__ out)
{
  __shared__ bf16_t lds_in[540*64];      // 69,120 B, XOR-swizzled 128B rows
  int bid = blockIdx.x;                  // 2048 = 8b x 32x x 4yg x 2zg
  int b  = bid >> 8;
  int x  = (bid >> 3) & 31;
  int y0 = ((bid >> 1) & 3) << 3;
  int z0 = (bid & 1) << 4;
  int t = threadIdx.x;
  for (int seg = t; seg < 540*8; seg += 256){
    int row = seg >> 3, part = seg & 7;
    int hx = row / 180, rem = row - hx*180;
    int hy = rem / 18,  hz = rem - hy*18;
    int gx = x + hx - 1, gy = y0 + hy - 1, gz = z0 + hz - 1;
    uint4 val = make_uint4(0u,0u,0u,0u);
    if ((unsigned)gx < 32u && (unsigned)gy < 32u && (unsigned)gz < 32u)
      val = *(const uint4*)(in + ((((size_t)(b*RR3 + ((gx<<10)+(gy<<5)+gz))) << 6) + part*8));
    *(uint4*)(lds_in + row*64 + ((part ^ (row & 7)) << 3)) = val;
  }
  int wave = t >> 6, lane = t & 63;
  int lz    = lane & 15;
  int yloc  = (lane >> 4) & 1;
  int khalf = lane >> 5;
  int ybase = 2*wave + yloc;             // local y 0..7 (pre-halo)
  f32x16 acc0 = 0.f, acc1 = 0.f;

  W8 wA, wB, wC;
  load_wfrag(wpack, 0, lane, wA);        // prefetch tap 0
  load_wfrag(wpack, 1, lane, wB);        // prefetch tap 1
  __syncthreads();                       // only barrier: input tile ready

#pragma unroll
  for (int p = 0; p < 9; ++p){
    int t0 = 3*p, t1 = 3*p+1, t2 = 3*p+2;
    int n0 = (t0+2 < 27) ? t0+2 : 26;
    int n1 = (t1+2 < 27) ? t1+2 : 26;
    int n2 = (t2+2 < 27) ? t2+2 : 26;
    load_wfrag(wpack, n0, lane, wC);
    { int dx = t0/9, r9 = t0-dx*9, dy = r9/3, dz = r9-dy*3;
      tap_mfma32(lds_in, dx*180 + (ybase+dy)*18 + lz + dz, khalf, wA, acc0, acc1); }
    load_wfrag(wpack, n1, lane, wA);
    { int dx = t1/9, r9 = t1-dx*9, dy = r9/3, dz = r9-dy*3;
      tap_mfma32(lds_in, dx*180 + (ybase+dy)*18 + lz + dz, khalf, wB, acc0, acc1); }
    load_wfrag(wpack, n2, lane, wB);
    { int dx = t2/9, r9 = t2-dx*9, dy = r9/3, dz = r9-dy*3;
      tap_mfma32(lds_in, dx*180 + (ybase+dy)*18 + lz + dz, khalf, wC, acc0, acc1); }
  }

  f32x16 accs[2] = {acc0, acc1};
  int co_l = lane & 31;
#pragma unroll
  for (int nt = 0; nt < 2; ++nt){
    int co = nt*32 + co_l;
    float sc = scale[co], sh = shift[co];
#pragma unroll
    for (int r = 0; r < 16; ++r){
      int m = (r & 3) + ((r >> 2) << 3) + 4*khalf;   // voxel 0..31
      int z  = m & 15;
      int yl = m >> 4;
      int y  = y0 + 2*wave + yl;
      size_t o = (((size_t)(b*RR3 + ((x<<10) + (y<<5) + z0 + z))) << 6) + co;
      float val = accs[nt][r]*sc + sh;
      val = fmaxf(val, 0.1f*val);                    // LeakyReLU(0.1)
      out[o] = (bf16_t)val;
    }
  }
}

// --------------------------------------------------------------- devoxelize + point branch
// Point-branch MLP (64x64, K=64, 32 points/block) on MFMA: 2 p-tiles x 4
// o-tiles of 16x16, wave owns (ptile = w&1, otiles {2*(w>>1)+u}). lw rows
// padded 64->72 elems (stride 144B == 4 banks -> conflict-free).
__global__ __launch_bounds__(256) void devox_kernel(
    const bf16_t* __restrict__ g,        // conv2 out [B*R3,64] channels-last
    const bf16_t* __restrict__ feat_t,   // [B*N,64] bf16 point-major
    const void* __restrict__ coords,
    const void* __restrict__ mlp_w,      // [64,64]
    const float* __restrict__ stats, const int* __restrict__ flag,
    const float* __restrict__ pscale, const float* __restrict__ pshift,
    void* __restrict__ out)              // [B,64,N]
{
  __shared__ bf16_t lf[32*72];           // feat tile [p][ci], padded
  __shared__ bf16_t lw[64*72];           // mlp_w [o][c], padded
  __shared__ float  lo[64*33];           // out tile [co][p]
  int t = threadIdx.x;
  int isf = *flag;
  int pb = blockIdx.x << 5;              // 32 points / block
  int b = pb >> 15, n0 = pb & (NPTS - 1);
  {
    int p = t >> 3, seg = t & 7;         // 256 threads == 32 points x 8 segs
    *(bf16x8*)(lf + p*72 + seg*8) =
        *(const bf16x8*)(feat_t + (((size_t)(b*NPTS + n0 + p)) << 6) + seg*8);
  }
  for (int i = t; i < 4096; i += 256){
    int o = i >> 6, c = i & 63;
    lw[o*72 + c] = (bf16_t)LD(mlp_w, i, isf);
  }
  __syncthreads();
  // ---- devoxelize gather (VALU), thread = (point p, channel-seg gseg) ----
  int p = t >> 3, gseg = t & 7;
  int n = n0 + p;
  float4 st = ((const float4*)stats)[b];
  int idx[8]; float wts[8];
  compute_corners(coords, st, b, n, isf, idx, wts);
  float dv[8] = {0,0,0,0,0,0,0,0};
#pragma unroll
  for (int k = 0; k < 8; ++k){
    bf16x8 gv = *(const bf16x8*)(g + (((size_t)(b*RR3 + idx[k])) << 6) + gseg*8);
    float w = wts[k];
#pragma unroll
    for (int j = 0; j < 8; ++j) dv[j] += w * (float)gv[j];
  }
#pragma unroll
  for (int j = 0; j < 8; ++j)
    lo[(gseg*8 + j)*33 + p] = dv[j];
  __syncthreads();
  // ---- point-branch MLP on MFMA ----
  int wave = t >> 6, lane = t & 63;
  int lrow = lane & 15, quad = lane >> 4;
  int ptile = wave & 1, og = wave >> 1;  // wave -> (ptile, otile pair)
  const bf16_t* arow = lf + (ptile*16 + lrow)*72;
  bf16x8 a0 = *(const bf16x8*)(arow + quad*8);
  bf16x8 a1 = *(const bf16x8*)(arow + 32 + quad*8);
#pragma unroll
  for (int u = 0; u < 2; ++u){
    int ot = og*2 + u;
    const bf16_t* brow = lw + (ot*16 + lrow)*72;
    bf16x8 b0 = *(const bf16x8*)(brow + quad*8);
    bf16x8 b1 = *(const bf16x8*)(brow + 32 + quad*8);
    f32x4 acc = 0.f;
    acc = __builtin_amdgcn_mfma_f32_16x16x32_bf16(a0, b0, acc, 0, 0, 0);
    acc = __builtin_amdgcn_mfma_f32_16x16x32_bf16(a1, b1, acc, 0, 0, 0);
    int o = ot*16 + lrow;
    float sc = pscale[o], sh = pshift[o];
#pragma unroll
    for (int r = 0; r < 4; ++r){
      int pl = ptile*16 + quad*4 + r;
      float q = fmaxf(acc[r]*sc + sh, 0.f);
      lo[o*33 + pl] += q;                // disjoint (o,pl) per wave: race-free
    }
  }
  __syncthreads();
  size_t obase = ((size_t)b << 21) + n0;
  if (isf){
    float* of = (float*)out;
    for (int i = t; i < 2048; i += 256){
      int co = i >> 5, pp = i & 31;
      of[obase + ((size_t)co << 15) + pp] = lo[co*33 + pp];
    }
  } else {
    bf16_t* oh = (bf16_t*)out;
    for (int i = t; i < 2048; i += 256){
      int co = i >> 5, pp = i & 31;
      oh[obase + ((size_t)co << 15) + pp] = (bf16_t)lo[co*33 + pp];
    }
  }
}

// --------------------------------------------------------------- coords passthrough
__global__ __launch_bounds__(256) void copy_coords_kernel(
    const void* __restrict__ coords, void* __restrict__ out, const int* __restrict__ flag){
  int i = blockIdx.x * 256 + threadIdx.x;
  if (i >= 786432) return;
  if (*flag) ((float*)out)[16777216 + i]  = ((const float*)coords)[i];
  else       ((bf16_t*)out)[16777216 + i] = ((const bf16_t*)coords)[i];
}

// --------------------------------------------------------------- param / weight prep
// fragment-major 32x32 weight pack: dst[tap][ntile][q][lane][e]
//   co = ntile*32 + lcol, ci = q*16 + khalf*8 + e, lane = khalf*32 + lcol
__global__ void prep_weights_kernel(const void* __restrict__ w1, const void* __restrict__ w2,
                                    const int* __restrict__ flag,
                                    bf16_t* __restrict__ wp1, bf16_t* __restrict__ wp2){
  int isf = *flag;
  int id = blockIdx.x * 256 + threadIdx.x;
  if (id >= 27*64*64) return;
  int off = id >> 12, co = (id >> 6) & 63, ci = id & 63;
  int src = (co*64 + ci)*27 + off;
  int ntile = co >> 5, lcol = co & 31;
  int q = ci >> 4, khalf = (ci >> 3) & 1, e = ci & 7;
  int dst = off*4096 + ntile*2048 + q*512 + (khalf*32 + lcol)*8 + e;
  wp1[dst] = (bf16_t)LD(w1, src, isf);
  wp2[dst] = (bf16_t)LD(w2, src, isf);
}

__global__ void prep_params_kernel(
    const void* c1b, const void* g1, const void* b1, const void* m1, const void* v1,
    const void* c2b, const void* g2, const void* b2, const void* m2, const void* v2,
    const void* pb_, const void* gp, const void* bp, const void* mp, const void* vp,
    const int* __restrict__ flag,
    float* __restrict__ P)   // [6][64]: s1, h1, s2, h2, sp, hp
{
  int isf = *flag;
  int c = threadIdx.x;
  if (c >= 64) return;
  float s1 = LD(g1,c,isf) / sqrtf(LD(v1,c,isf) + 1e-4f);
  P[c]       = s1;
  P[64 + c]  = (LD(c1b,c,isf) - LD(m1,c,isf))*s1 + LD(b1,c,isf);
  float s2 = LD(g2,c,isf) / sqrtf(LD(v2,c,isf) + 1e-4f);
  P[128 + c] = s2;
  P[192 + c] = (LD(c2b,c,isf) - LD(m2,c,isf))*s2 + LD(b2,c,isf);
  float sp = LD(gp,c,isf) / sqrtf(LD(vp,c,isf) + 1e-4f);
  P[256 + c] = sp;
  P[320 + c] = (LD(pb_,c,isf) - LD(mp,c,isf))*sp + LD(bp,c,isf);
}

// --------------------------------------------------------------- launch
extern "C" void kernel_launch(void* const* d_in, const int* in_sizes, int n_in,
                              void* d_out, int out_size, void* d_ws, size_t ws_size,
                              hipStream_t stream)
{
  const void* feat   = d_in[0];
  const void* coords = d_in[1];
  const void* c1w = d_in[2];
  const void* c1b = d_in[3];
  const void* g1  = d_in[4];
  const void* b1  = d_in[5];
  const void* m1  = d_in[6];
  const void* v1  = d_in[7];
  const void* c2w = d_in[8];
  const void* c2b = d_in[9];
  const void* g2  = d_in[10];
  const void* b2  = d_in[11];
  const void* m2  = d_in[12];
  const void* v2  = d_in[13];
  const void* mw  = d_in[14];
  const void* mb  = d_in[15];
  const void* gp  = d_in[16];
  const void* bp  = d_in[17];
  const void* mp  = d_in[18];
  const void* vp  = d_in[19];

  char* ws = (char*)d_ws;
  bf16_t*  feat_t  = (bf16_t*)(ws);                     // 33,554,432 B
  bf16_t*  vox     = (bf16_t*)(ws + 33554432);          // 33,554,432 B
  bf16_t*  c1out   = (bf16_t*)(ws + 67108864);          // 33,554,432 B
  bf16_t*  c2out   = vox;                               // vox dead after conv1
  uint2*   sorted  = (uint2*)(ws + 100663296);          // 16,777,216 B
  unsigned* hist   = (unsigned*)(ws + 117440512);       //  1,048,576 B
  unsigned* offs   = (unsigned*)(ws + 118489088);       //  1,048,576 B
  bf16_t*  wp1     = (bf16_t*)(ws + 119537664);         //    221,184 B
  bf16_t*  wp2     = (bf16_t*)(ws + 119758848);         //    221,184 B
  float*   P       = (float*)(ws + 119980032);          //      1,536 B
  float*   stats   = (float*)(ws + 119981568);          //        128 B
  int*     flag    = (int*)(ws + 119981696);            //        128 B
  unsigned* counter= (unsigned*)(ws + 119981824);       //        128 B
  float*   ssum    = (float*)(ws + 119981952);          //        128 B (8x4 f32)
  unsigned* smax   = (unsigned*)(ws + 119982080);       //        128 B

  hipMemsetAsync(flag, 0, 4, stream);
  hipMemsetAsync(hist, 0, 1048576, stream);
  hipMemsetAsync(counter, 0, 4, stream);
  hipMemsetAsync(ssum, 0, 256, stream);                 // ssum + smax
  detect_kernel<<<3072, 256, 0, stream>>>(coords, flag);
  prep_weights_kernel<<<432, 256, 0, stream>>>(c1w, c2w, flag, wp1, wp2);
  prep_params_kernel<<<1, 64, 0, stream>>>(c1b,g1,b1,m1,v1, c2b,g2,b2,m2,v2,
                                           mb,gp,bp,mp,vp, flag, P);
  stats_sum_kernel<<<256, 256, 0, stream>>>(coords, flag, ssum);
  stats_max_kernel<<<256, 256, 0, stream>>>(coords, flag, ssum, smax);
  stats_fin_kernel<<<1, 64, 0, stream>>>(ssum, smax, stats);
  transpose_kernel<<<4096, 256, 0, stream>>>(feat, flag, feat_t);
  hist_kernel<<<1024, 256, 0, stream>>>(coords, stats, flag, hist);
  offsets_kernel<<<1024, 256, 0, stream>>>(hist, offs, counter);
  fill_kernel<<<1024, 256, 0, stream>>>(coords, stats, flag, offs, sorted);
  gather_kernel<<<2048, 256, 0, stream>>>(sorted, offs, hist, feat_t, vox);
  conv3d_kernel<<<2048, 256, 0, stream>>>(vox,   wp1, P,       P + 64,  c1out);
  conv3d_kernel<<<2048, 256, 0, stream>>>(c1out, wp2, P + 128, P + 192, c2out);
  devox_kernel<<<8192, 256, 0, stream>>>(c2out, feat_t, coords, mw, stats, flag,
                                         P + 256, P + 320, d_out);
  copy_coords_kernel<<<3072, 256, 0, stream>>>(coords, d_out, flag);
}

// Round 10
// 597.447 us; speedup vs baseline: 1.6517x; 1.1922x over previous
//
#include <hip/hip_runtime.h>
#include <cstdint>
#include <cstddef>

#define NPTS  32768
#define NB    8
#define RR    32
#define RR3   32768
#define NVOX  (NB*RR3)          // 262144

typedef __bf16 bf16_t;
typedef __bf16 bf16x8 __attribute__((ext_vector_type(8)));
typedef __bf16 bf16x4 __attribute__((ext_vector_type(4)));
typedef float  f32x4  __attribute__((ext_vector_type(4)));
typedef float  f32x16 __attribute__((ext_vector_type(16)));

// adaptive load: input tensors may be fp32 or bf16 (detected at runtime)
__device__ __forceinline__ float LD(const void* p, size_t i, int isf){
  return isf ? ((const float*)p)[i] : (float)((const bf16_t*)p)[i];
}

// ---------------------------------------------------------------- reductions
__device__ __forceinline__ float wave_sum(float v){
#pragma unroll
  for (int o = 32; o > 0; o >>= 1) v += __shfl_down(v, o, 64);
  return v;
}
__device__ __forceinline__ float wave_max(float v){
#pragma unroll
  for (int o = 32; o > 0; o >>= 1) v = fmaxf(v, __shfl_down(v, o, 64));
  return v;
}

// --------------------------------------------------------------- dtype detect (parallel)
__global__ __launch_bounds__(256) void detect_kernel(const void* __restrict__ coords,
                                                     int* __restrict__ flag){
  int i = blockIdx.x*256 + threadIdx.x;
  const uint16_t* p = (const uint16_t*)coords;
  if ((p[i] & 0x7F80) == 0x7F80) atomicOr(flag, 1);   // 1 = fp32
}

// --------------------------------------------------------------- stats (3-phase parallel)
__global__ __launch_bounds__(256) void stats_sum_kernel(
    const void* __restrict__ coords, const int* __restrict__ flag, float* __restrict__ ssum){
  __shared__ float l[12];
  int isf = *flag;
  int b = blockIdx.x >> 5, blk = blockIdx.x & 31;     // 32 blocks per batch
  int t = threadIdx.x;
  size_t cb = ((size_t)b * 3) << 15;
  float sx = 0.f, sy = 0.f, sz = 0.f;
  int n0 = blk << 10;
  for (int n = n0 + t; n < n0 + 1024; n += 256){
    sx += LD(coords, cb + n, isf);
    sy += LD(coords, cb + NPTS + n, isf);
    sz += LD(coords, cb + 2*NPTS + n, isf);
  }
  sx = wave_sum(sx); sy = wave_sum(sy); sz = wave_sum(sz);
  int w = t >> 6;
  if ((t & 63) == 0){ l[w] = sx; l[4+w] = sy; l[8+w] = sz; }
  __syncthreads();
  if (t == 0){
    unsafeAtomicAdd(&ssum[b*4+0], l[0]+l[1]+l[2]+l[3]);
    unsafeAtomicAdd(&ssum[b*4+1], l[4]+l[5]+l[6]+l[7]);
    unsafeAtomicAdd(&ssum[b*4+2], l[8]+l[9]+l[10]+l[11]);
  }
}

__global__ __launch_bounds__(256) void stats_max_kernel(
    const void* __restrict__ coords, const int* __restrict__ flag,
    const float* __restrict__ ssum, unsigned* __restrict__ smax){
  __shared__ float l[4];
  int isf = *flag;
  int b = blockIdx.x >> 5, blk = blockIdx.x & 31;
  int t = threadIdx.x;
  size_t cb = ((size_t)b * 3) << 15;
  float mx = ssum[b*4+0] * (1.f/NPTS);
  float my = ssum[b*4+1] * (1.f/NPTS);
  float mz = ssum[b*4+2] * (1.f/NPTS);
  float mm = 0.f;
  int n0 = blk << 10;
  for (int n = n0 + t; n < n0 + 1024; n += 256){
    float cx = LD(coords, cb + n, isf) - mx;
    float cy = LD(coords, cb + NPTS + n, isf) - my;
    float cz = LD(coords, cb + 2*NPTS + n, isf) - mz;
    mm = fmaxf(mm, cx*cx + cy*cy + cz*cz);
  }
  mm = wave_max(mm);
  int w = t >> 6;
  if ((t & 63) == 0) l[w] = mm;
  __syncthreads();
  if (t == 0){
    float m = fmaxf(fmaxf(l[0], l[1]), fmaxf(l[2], l[3]));
    atomicMax(&smax[b], __float_as_uint(m));          // valid: m >= 0
  }
}

__global__ void stats_fin_kernel(const float* __restrict__ ssum,
                                 const unsigned* __restrict__ smax,
                                 float* __restrict__ stats){
  int b = threadIdx.x;
  if (b >= NB) return;
  float m = __uint_as_float(smax[b]);
  float inv = 32.f / (2.f * sqrtf(m) * (1.f + 1e-6f));
  float4 o;
  o.x = ssum[b*4+0] * (1.f/NPTS);
  o.y = ssum[b*4+1] * (1.f/NPTS);
  o.z = ssum[b*4+2] * (1.f/NPTS);
  o.w = inv;
  ((float4*)stats)[b] = o;
}

// --------------------------------------------------------------- corners (devox only)
__device__ __forceinline__ void compute_corners(const void* __restrict__ coords, float4 st,
                                                int b, int n, int isf, int* idx, float* wts){
  size_t cbase = ((size_t)b * 3) << 15;
  float cx = LD(coords, cbase + n, isf)          - st.x;
  float cy = LD(coords, cbase + NPTS + n, isf)   - st.y;
  float cz = LD(coords, cbase + 2*NPTS + n, isf) - st.z;
  float vx = fminf(fmaxf(cx*st.w + 16.f, 0.f), 31.f);
  float vy = fminf(fmaxf(cy*st.w + 16.f, 0.f), 31.f);
  float vz = fminf(fmaxf(cz*st.w + 16.f, 0.f), 31.f);
  int lx = (int)vx, ly = (int)vy, lz = (int)vz;
  float fx = vx - (float)lx, fy = vy - (float)ly, fz = vz - (float)lz;
#pragma unroll
  for (int k = 0; k < 8; ++k){
    int dx = k >> 2, dy = (k >> 1) & 1, dz = k & 1;
    int xi = min(lx+dx, 31), yi = min(ly+dy, 31), zi = min(lz+dz, 31);
    idx[k] = (xi << 10) + (yi << 5) + zi;
    wts[k] = (dx ? fx : 1.f-fx) * (dy ? fy : 1.f-fy) * (dz ? fz : 1.f-fz);
  }
}

// floor voxel + fractions (voxelize path)
__device__ __forceinline__ void compute_floor(const void* __restrict__ coords, float4 st,
                                              int b, int n, int isf,
                                              int& fv, float& fx, float& fy, float& fz){
  size_t cbase = ((size_t)b * 3) << 15;
  float cx = LD(coords, cbase + n, isf)          - st.x;
  float cy = LD(coords, cbase + NPTS + n, isf)   - st.y;
  float cz = LD(coords, cbase + 2*NPTS + n, isf) - st.z;
  float vx = fminf(fmaxf(cx*st.w + 16.f, 0.f), 31.f);
  float vy = fminf(fmaxf(cy*st.w + 16.f, 0.f), 31.f);
  float vz = fminf(fmaxf(cz*st.w + 16.f, 0.f), 31.f);
  int lx = (int)vx, ly = (int)vy, lz = (int)vz;
  fx = vx - (float)lx; fy = vy - (float)ly; fz = vz - (float)lz;
  fv = (lx << 10) + (ly << 5) + lz;
}

// --------------------------------------------------------------- transpose feat -> [B*N,64] bf16
__global__ __launch_bounds__(256) void transpose_kernel(
    const void* __restrict__ feat, const int* __restrict__ flag, bf16_t* __restrict__ feat_t)
{
  __shared__ float tile[64][65];
  int isf = *flag;
  int blk = blockIdx.x;            // 4096 = B * (N/64)
  int b = blk >> 9;
  int n0 = (blk & 511) << 6;
  int t = threadIdx.x, lane = t & 63, w = t >> 6;
  size_t base = ((size_t)b << 21); // b*64*N
  for (int ci = w; ci < 64; ci += 4)
    tile[ci][lane] = LD(feat, base + ((size_t)ci << 15) + n0 + lane, isf);
  __syncthreads();
  for (int i = t; i < 512; i += 256){
    int p = i >> 3, seg = i & 7;
    bf16x8 o;
#pragma unroll
    for (int e = 0; e < 8; ++e) o[e] = (bf16_t)tile[seg*8+e][p];
    *(bf16x8*)(feat_t + (((size_t)(b*NPTS + n0 + p)) << 6) + seg*8) = o;
  }
}

// --------------------------------------------------------------- voxelize: FLOOR-based
// Round-9 PMC: 2.1M device-scope atomics cost ~100us regardless of XCD
// locality (hist 102us, slab-localized fill ~100us; ~20 atomics/ns device
// floor -> memory-side RMW). Fix: sort by FLOOR voxel only (1 atomic/point =
// 262K, 8x fewer) storing (n,fx,fy,fz); gather expands the 8 corners by
// walking the <=4 contiguous floor-cell ranges {x-1,x}x{y-1,y}x{z-1,z} and
// computing weights on the fly. Clamped duplicate corners have fx==0 -> w==0
// -> contribute nothing to acc OR cw (normalizer is sum-of-w), so clamping
// can be ignored entirely.
__global__ __launch_bounds__(256) void hist_kernel(
    const void* __restrict__ coords, const float* __restrict__ stats,
    const int* __restrict__ flag, unsigned* __restrict__ hist)
{
  int isf = *flag;
  int gid = blockIdx.x*256 + threadIdx.x;
  int b = gid >> 15, n = gid & (NPTS-1);
  float4 st = ((const float4*)stats)[b];
  int fv; float fx, fy, fz;
  compute_floor(coords, st, b, n, isf, fv, fx, fy, fz);
  atomicAdd(&hist[(b << 15) + fv], 1u);
}

__global__ __launch_bounds__(256) void offsets_kernel(
    const unsigned* __restrict__ hist, unsigned* __restrict__ offsets,
    unsigned* __restrict__ counter)
{
  int v = blockIdx.x*256 + threadIdx.x;
  int lane = threadIdx.x & 63;
  unsigned h = hist[v];
  unsigned pre = h;
#pragma unroll
  for (int o = 1; o < 64; o <<= 1){
    unsigned x = __shfl_up(pre, o, 64);
    if (lane >= o) pre += x;
  }
  unsigned total = __shfl(pre, 63, 64);
  unsigned base = 0;
  if (lane == 63) base = atomicAdd(counter, total);
  base = __shfl(base, 63, 64);
  offsets[v] = base + pre - h;      // exclusive start of segment v
}

__global__ __launch_bounds__(256) void fill_kernel(
    const void* __restrict__ coords, const float* __restrict__ stats,
    const int* __restrict__ flag, unsigned* __restrict__ offsets,
    uint4* __restrict__ sortedF)
{
  int isf = *flag;
  int gid = blockIdx.x*256 + threadIdx.x;
  int b = gid >> 15, n = gid & (NPTS-1);
  float4 st = ((const float4*)stats)[b];
  int fv; float fx, fy, fz;
  compute_floor(coords, st, b, n, isf, fv, fx, fy, fz);
  unsigned pos = atomicAdd(&offsets[(b << 15) + fv], 1u);   // bump to segment end
  sortedF[pos] = make_uint4((unsigned)n, __float_as_uint(fx),
                            __float_as_uint(fy), __float_as_uint(fz));
}

// PERSISTENT gather with corner expansion: 1024 blocks x 4 waves = 4096 waves,
// each wave owns 64 voxels v = ((wid*64+k)*M) & (NVOX-1) (bijective scatter,
// balances the Gaussian-center density). Per voxel: 4 contiguous ranges
// (cells (x',y',z-1..z), x' in {x-1,x}, y' in {y-1,y}); virtual index j over
// their concatenation keeps the 8-slot x 8-deep load batching. Weight per
// entry: wx = xi?fx:1-fx, wy = yi?fy:1-fy, wz = (pos>=mid)?1-fz:fz.
__global__ __launch_bounds__(256) void gather_kernel(
    const uint4* __restrict__ sortedF, const unsigned* __restrict__ offs_end,
    const unsigned* __restrict__ hist, const bf16_t* __restrict__ feat_t,
    bf16_t* __restrict__ vox)
{
  const unsigned M = 162005u;          // odd -> bijective scatter mod 2^18
  int wid = blockIdx.x*4 + (threadIdx.x >> 6);
  int lane = threadIdx.x & 63;
  int g  = lane >> 3;                  // entry slot group
  int c8 = lane & 7;                   // 8 bf16 channels (16B) per lane

#pragma unroll 1
  for (int k = 0; k < 64; ++k){
    int v = (int)((((unsigned)wid << 6) | (unsigned)k) * M & (NVOX - 1u));
    int b = v >> 15;
    int x = (v >> 10) & 31, y = (v >> 5) & 31, z = v & 31;
    int boff = b << 15;
    int zlo = (z > 0) ? z - 1 : z;
    int zspan = z - zlo;               // 1 if z>0 else 0
    // ---- 4 ranges: r = (xi<<1)|yi, cell x' = x-xi, y' = y-yi ----
    unsigned st0=0, md0=0, ln0=0, st1=0, md1=0, ln1=0;
    unsigned st2=0, md2=0, ln2=0, st3=0, md3=0, ln3=0;
    {
      int c0 = boff + (x<<10) + (y<<5) + zlo;
      unsigned e0 = offs_end[c0], h0 = hist[c0], e1 = offs_end[c0 + zspan];
      st0 = e0 - h0; md0 = (z > 0) ? e0 : st0; ln0 = e1 - st0;
    }
    if (y > 0){
      int c0 = boff + (x<<10) + ((y-1)<<5) + zlo;
      unsigned e0 = offs_end[c0], h0 = hist[c0], e1 = offs_end[c0 + zspan];
      st1 = e0 - h0; md1 = (z > 0) ? e0 : st1; ln1 = e1 - st1;
    }
    if (x > 0){
      int c0 = boff + ((x-1)<<10) + (y<<5) + zlo;
      unsigned e0 = offs_end[c0], h0 = hist[c0], e1 = offs_end[c0 + zspan];
      st2 = e0 - h0; md2 = (z > 0) ? e0 : st2; ln2 = e1 - st2;
    }
    if (x > 0 && y > 0){
      int c0 = boff + ((x-1)<<10) + ((y-1)<<5) + zlo;
      unsigned e0 = offs_end[c0], h0 = hist[c0], e1 = offs_end[c0 + zspan];
      st3 = e0 - h0; md3 = (z > 0) ? e0 : st3; ln3 = e1 - st3;
    }
    unsigned L0 = ln0, L01 = L0 + ln1, L012 = L01 + ln2, total = L012 + ln3;
    if (total == 0){
      if (g == 0){
        bf16x8 zr;
#pragma unroll
        for (int j = 0; j < 8; ++j) zr[j] = (bf16_t)0.f;
        *(bf16x8*)(vox + ((size_t)v << 6) + c8*8) = zr;
      }
      continue;
    }
    unsigned adj0 = st0;               // pos = j + adj_r (unsigned wrap ok)
    unsigned adj1 = st1 - L0;
    unsigned adj2 = st2 - L01;
    unsigned adj3 = st3 - L012;
    size_t fbase = ((size_t)b << 21);  // b*NPTS*64
    float acc[8] = {0.f,0.f,0.f,0.f,0.f,0.f,0.f,0.f};
    float cw = 0.f;
    for (unsigned jb = 0; jb < total; jb += 64){
      uint4 e[8];
#pragma unroll
      for (int d = 0; d < 8; ++d){
        unsigned j = jb + g + 8*d;
        unsigned cA = (j >= L0), cB = (j >= L01), cC = (j >= L012);
        unsigned adj = cB ? (cC ? adj3 : adj2) : (cA ? adj1 : adj0);
        unsigned pos = (j < total) ? (j + adj) : 0u;    // pad -> entry 0 (valid n)
        e[d] = sortedF[pos];
      }
      bf16x8 f[8];
#pragma unroll
      for (int d = 0; d < 8; ++d)
        f[d] = *(const bf16x8*)(feat_t + fbase + ((size_t)e[d].x << 6) + c8*8);
#pragma unroll
      for (int d = 0; d < 8; ++d){
        unsigned j = jb + g + 8*d;
        unsigned cA = (j >= L0), cB = (j >= L01), cC = (j >= L012);
        unsigned adj = cB ? (cC ? adj3 : adj2) : (cA ? adj1 : adj0);
        unsigned mid = cB ? (cC ? md3 : md2) : (cA ? md1 : md0);
        unsigned pos = j + adj;
        unsigned xi = cB, yi = cA ^ cB ^ cC;
        float fx = __uint_as_float(e[d].y);
        float fy = __uint_as_float(e[d].z);
        float fz = __uint_as_float(e[d].w);
        float w = (xi ? fx : 1.f-fx) * (yi ? fy : 1.f-fy)
                * ((pos >= mid) ? 1.f-fz : fz);
        w = (j < total) ? w : 0.f;
#pragma unroll
        for (int q = 0; q < 8; ++q) acc[q] += w * (float)f[d][q];
        cw += w;
      }
    }
    // combine the 8 entry-slot groups (lanes differing in bits 3,4,5)
#pragma unroll
    for (int m = 8; m < 64; m <<= 1){
#pragma unroll
      for (int q = 0; q < 8; ++q) acc[q] += __shfl_xor(acc[q], m, 64);
      cw += __shfl_xor(cw, m, 64);
    }
    if (g == 0){
      float inv = 1.f / fmaxf(cw, 1e-8f);
      bf16x8 o;
#pragma unroll
      for (int q = 0; q < 8; ++q) o[q] = (bf16_t)(acc[q]*inv);
      *(bf16x8*)(vox + ((size_t)v << 6) + c8*8) = o;
    }
  }
}

// --------------------------------------------------------------- conv3d 3x3x3 + BN + LeakyReLU
// channels-last in/out [B*R3, 64]; tile: x fixed, y0..y0+7, z0..z0+15 (128
// voxels / wg, wave = 2 y-rows = M=32). mfma_f32_32x32x16 (2x FLOP per weight
// byte vs 16x16) + 128-voxel tile -> 1.77 GB/dispatch weight traffic. Weights
// as per-wave REGISTER fragments from a 32x32 fragment-major pack, 3-buffer
// rotation, ZERO barriers in the tap loop. Input tile XOR-swizzled 128B rows.
//   A: row = lane&31, k = (lane>>5)*8 + e
//   B: col = lane&31, k = (lane>>5)*8 + e
//   D: col = lane&31, row = (reg&3) + 8*(reg>>2) + 4*(lane>>5)
struct W8 { bf16x8 v[8]; };

__device__ __forceinline__ void load_wfrag(const bf16_t* __restrict__ wpack, int tap, int lane, W8& w){
#pragma unroll
  for (int f = 0; f < 8; ++f)
    w.v[f] = *(const bf16x8*)(wpack + (size_t)(tap*8 + f)*512 + lane*8);
}

__device__ __forceinline__ void tap_mfma32(const bf16_t* lds_in, int rowidx, int khalf, const W8& w,
                                           f32x16& a0, f32x16& a1){
  int swz = rowidx & 7;
  const bf16_t* aptr = lds_in + rowidx*64;
#pragma unroll
  for (int q = 0; q < 4; ++q){
    bf16x8 a = *(const bf16x8*)(aptr + ((((q<<1)|khalf) ^ swz) << 3));
    a0 = __builtin_amdgcn_mfma_f32_32x32x16_bf16(a, w.v[q],   a0, 0, 0, 0);
    a1 = __builtin_amdgcn_mfma_f32_32x32x16_bf16(a, w.v[4+q], a1, 0, 0, 0);
  }
}

__global__ __launch_bounds__(256, 2) void conv3d_kernel(
    const bf16_t* __restrict__ in, const bf16_t* __restrict__ wpack,   // frag-major [27][nt2][q4][64][8]
    const float* __restrict__ scale, const float* __restrict__ shift,
    bf16_t* __restrict__ out)
{
  __shared__ bf16_t lds_in[540*64];      // 69,120 B, XOR-swizzled 128B rows
  int bid = blockIdx.x;                  // 2048 = 8b x 32x x 4yg x 2zg
  int b  = bid >> 8;
  int x  = (bid >> 3) & 31;
  int y0 = ((bid >> 1) & 3) << 3;
  int z0 = (bid & 1) << 4;
  int t = threadIdx.x;
  for (int seg = t; seg < 540*8; seg += 256){
    int row = seg >> 3, part = seg & 7;
    int hx = row / 180, rem = row - hx*180;
    int hy = rem / 18,  hz = rem - hy*18;
    int gx = x + hx - 1, gy = y0 + hy - 1, gz = z0 + hz - 1;
    uint4 val = make_uint4(0u,0u,0u,0u);
    if ((unsigned)gx < 32u && (unsigned)gy < 32u && (unsigned)gz < 32u)
      val = *(const uint4*)(in + ((((size_t)(b*RR3 + ((gx<<10)+(gy<<5)+gz))) << 6) + part*8));
    *(uint4*)(lds_in + row*64 + ((part ^ (row & 7)) << 3)) = val;
  }
  int wave = t >> 6, lane = t & 63;
  int lz    = lane & 15;
  int yloc  = (lane >> 4) & 1;
  int khalf = lane >> 5;
  int ybase = 2*wave + yloc;             // local y 0..7 (pre-halo)
  f32x16 acc0 = 0.f, acc1 = 0.f;

  W8 wA, wB, wC;
  load_wfrag(wpack, 0, lane, wA);        // prefetch tap 0
  load_wfrag(wpack, 1, lane, wB);        // prefetch tap 1
  __syncthreads();                       // only barrier: input tile ready

#pragma unroll
  for (int p = 0; p < 9; ++p){
    int t0 = 3*p, t1 = 3*p+1, t2 = 3*p+2;
    int n0 = (t0+2 < 27) ? t0+2 : 26;
    int n1 = (t1+2 < 27) ? t1+2 : 26;
    int n2 = (t2+2 < 27) ? t2+2 : 26;
    load_wfrag(wpack, n0, lane, wC);
    { int dx = t0/9, r9 = t0-dx*9, dy = r9/3, dz = r9-dy*3;
      tap_mfma32(lds_in, dx*180 + (ybase+dy)*18 + lz + dz, khalf, wA, acc0, acc1); }
    load_wfrag(wpack, n1, lane, wA);
    { int dx = t1/9, r9 = t1-dx*9, dy = r9/3, dz = r9-dy*3;
      tap_mfma32(lds_in, dx*180 + (ybase+dy)*18 + lz + dz, khalf, wB, acc0, acc1); }
    load_wfrag(wpack, n2, lane, wB);
    { int dx = t2/9, r9 = t2-dx*9, dy = r9/3, dz = r9-dy*3;
      tap_mfma32(lds_in, dx*180 + (ybase+dy)*18 + lz + dz, khalf, wC, acc0, acc1); }
  }

  f32x16 accs[2] = {acc0, acc1};
  int co_l = lane & 31;
#pragma unroll
  for (int nt = 0; nt < 2; ++nt){
    int co = nt*32 + co_l;
    float sc = scale[co], sh = shift[co];
#pragma unroll
    for (int r = 0; r < 16; ++r){
      int m = (r & 3) + ((r >> 2) << 3) + 4*khalf;   // voxel 0..31
      int z  = m & 15;
      int yl = m >> 4;
      int y  = y0 + 2*wave + yl;
      size_t o = (((size_t)(b*RR3 + ((x<<10) + (y<<5) + z0 + z))) << 6) + co;
      float val = accs[nt][r]*sc + sh;
      val = fmaxf(val, 0.1f*val);                    // LeakyReLU(0.1)
      out[o] = (bf16_t)val;
    }
  }
}

// --------------------------------------------------------------- devoxelize + point branch
// Point-branch MLP (64x64, K=64, 32 points/block) on MFMA: 2 p-tiles x 4
// o-tiles of 16x16, wave owns (ptile = w&1, otiles {2*(w>>1)+u}). lw rows
// padded 64->72 elems (stride 144B == 4 banks -> conflict-free).
__global__ __launch_bounds__(256) void devox_kernel(
    const bf16_t* __restrict__ g,        // conv2 out [B*R3,64] channels-last
    const bf16_t* __restrict__ feat_t,   // [B*N,64] bf16 point-major
    const void* __restrict__ coords,
    const void* __restrict__ mlp_w,      // [64,64]
    const float* __restrict__ stats, const int* __restrict__ flag,
    const float* __restrict__ pscale, const float* __restrict__ pshift,
    void* __restrict__ out)              // [B,64,N]
{
  __shared__ bf16_t lf[32*72];           // feat tile [p][ci], padded
  __shared__ bf16_t lw[64*72];           // mlp_w [o][c], padded
  __shared__ float  lo[64*33];           // out tile [co][p]
  int t = threadIdx.x;
  int isf = *flag;
  int pb = blockIdx.x << 5;              // 32 points / block
  int b = pb >> 15, n0 = pb & (NPTS - 1);
  {
    int p = t >> 3, seg = t & 7;         // 256 threads == 32 points x 8 segs
    *(bf16x8*)(lf + p*72 + seg*8) =
        *(const bf16x8*)(feat_t + (((size_t)(b*NPTS + n0 + p)) << 6) + seg*8);
  }
  for (int i = t; i < 4096; i += 256){
    int o = i >> 6, c = i & 63;
    lw[o*72 + c] = (bf16_t)LD(mlp_w, i, isf);
  }
  __syncthreads();
  // ---- devoxelize gather (VALU), thread = (point p, channel-seg gseg) ----
  int p = t >> 3, gseg = t & 7;
  int n = n0 + p;
  float4 st = ((const float4*)stats)[b];
  int idx[8]; float wts[8];
  compute_corners(coords, st, b, n, isf, idx, wts);
  float dv[8] = {0,0,0,0,0,0,0,0};
#pragma unroll
  for (int k = 0; k < 8; ++k){
    bf16x8 gv = *(const bf16x8*)(g + (((size_t)(b*RR3 + idx[k])) << 6) + gseg*8);
    float w = wts[k];
#pragma unroll
    for (int j = 0; j < 8; ++j) dv[j] += w * (float)gv[j];
  }
#pragma unroll
  for (int j = 0; j < 8; ++j)
    lo[(gseg*8 + j)*33 + p] = dv[j];
  __syncthreads();
  // ---- point-branch MLP on MFMA ----
  int wave = t >> 6, lane = t & 63;
  int lrow = lane & 15, quad = lane >> 4;
  int ptile = wave & 1, og = wave >> 1;  // wave -> (ptile, otile pair)
  const bf16_t* arow = lf + (ptile*16 + lrow)*72;
  bf16x8 a0 = *(const bf16x8*)(arow + quad*8);
  bf16x8 a1 = *(const bf16x8*)(arow + 32 + quad*8);
#pragma unroll
  for (int u = 0; u < 2; ++u){
    int ot = og*2 + u;
    const bf16_t* brow = lw + (ot*16 + lrow)*72;
    bf16x8 b0 = *(const bf16x8*)(brow + quad*8);
    bf16x8 b1 = *(const bf16x8*)(brow + 32 + quad*8);
    f32x4 acc = 0.f;
    acc = __builtin_amdgcn_mfma_f32_16x16x32_bf16(a0, b0, acc, 0, 0, 0);
    acc = __builtin_amdgcn_mfma_f32_16x16x32_bf16(a1, b1, acc, 0, 0, 0);
    int o = ot*16 + lrow;
    float sc = pscale[o], sh = pshift[o];
#pragma unroll
    for (int r = 0; r < 4; ++r){
      int pl = ptile*16 + quad*4 + r;
      float q = fmaxf(acc[r]*sc + sh, 0.f);
      lo[o*33 + pl] += q;                // disjoint (o,pl) per wave: race-free
    }
  }
  __syncthreads();
  size_t obase = ((size_t)b << 21) + n0;
  if (isf){
    float* of = (float*)out;
    for (int i = t; i < 2048; i += 256){
      int co = i >> 5, pp = i & 31;
      of[obase + ((size_t)co << 15) + pp] = lo[co*33 + pp];
    }
  } else {
    bf16_t* oh = (bf16_t*)out;
    for (int i = t; i < 2048; i += 256){
      int co = i >> 5, pp = i & 31;
      oh[obase + ((size_t)co << 15) + pp] = (bf16_t)lo[co*33 + pp];
    }
  }
}

// --------------------------------------------------------------- coords passthrough
__global__ __launch_bounds__(256) void copy_coords_kernel(
    const void* __restrict__ coords, void* __restrict__ out, const int* __restrict__ flag){
  int i = blockIdx.x * 256 + threadIdx.x;
  if (i >= 786432) return;
  if (*flag) ((float*)out)[16777216 + i]  = ((const float*)coords)[i];
  else       ((bf16_t*)out)[16777216 + i] = ((const bf16_t*)coords)[i];
}

// --------------------------------------------------------------- param / weight prep
// fragment-major 32x32 weight pack: dst[tap][ntile][q][lane][e]
//   co = ntile*32 + lcol, ci = q*16 + khalf*8 + e, lane = khalf*32 + lcol
__global__ void prep_weights_kernel(const void* __restrict__ w1, const void* __restrict__ w2,
                                    const int* __restrict__ flag,
                                    bf16_t* __restrict__ wp1, bf16_t* __restrict__ wp2){
  int isf = *flag;
  int id = blockIdx.x * 256 + threadIdx.x;
  if (id >= 27*64*64) return;
  int off = id >> 12, co = (id >> 6) & 63, ci = id & 63;
  int src = (co*64 + ci)*27 + off;
  int ntile = co >> 5, lcol = co & 31;
  int q = ci >> 4, khalf = (ci >> 3) & 1, e = ci & 7;
  int dst = off*4096 + ntile*2048 + q*512 + (khalf*32 + lcol)*8 + e;
  wp1[dst] = (bf16_t)LD(w1, src, isf);
  wp2[dst] = (bf16_t)LD(w2, src, isf);
}

__global__ void prep_params_kernel(
    const void* c1b, const void* g1, const void* b1, const void* m1, const void* v1,
    const void* c2b, const void* g2, const void* b2, const void* m2, const void* v2,
    const void* pb_, const void* gp, const void* bp, const void* mp, const void* vp,
    const int* __restrict__ flag,
    float* __restrict__ P)   // [6][64]: s1, h1, s2, h2, sp, hp
{
  int isf = *flag;
  int c = threadIdx.x;
  if (c >= 64) return;
  float s1 = LD(g1,c,isf) / sqrtf(LD(v1,c,isf) + 1e-4f);
  P[c]       = s1;
  P[64 + c]  = (LD(c1b,c,isf) - LD(m1,c,isf))*s1 + LD(b1,c,isf);
  float s2 = LD(g2,c,isf) / sqrtf(LD(v2,c,isf) + 1e-4f);
  P[128 + c] = s2;
  P[192 + c] = (LD(c2b,c,isf) - LD(m2,c,isf))*s2 + LD(b2,c,isf);
  float sp = LD(gp,c,isf) / sqrtf(LD(vp,c,isf) + 1e-4f);
  P[256 + c] = sp;
  P[320 + c] = (LD(pb_,c,isf) - LD(mp,c,isf))*sp + LD(bp,c,isf);
}

// --------------------------------------------------------------- launch
extern "C" void kernel_launch(void* const* d_in, const int* in_sizes, int n_in,
                              void* d_out, int out_size, void* d_ws, size_t ws_size,
                              hipStream_t stream)
{
  const void* feat   = d_in[0];
  const void* coords = d_in[1];
  const void* c1w = d_in[2];
  const void* c1b = d_in[3];
  const void* g1  = d_in[4];
  const void* b1  = d_in[5];
  const void* m1  = d_in[6];
  const void* v1  = d_in[7];
  const void* c2w = d_in[8];
  const void* c2b = d_in[9];
  const void* g2  = d_in[10];
  const void* b2  = d_in[11];
  const void* m2  = d_in[12];
  const void* v2  = d_in[13];
  const void* mw  = d_in[14];
  const void* mb  = d_in[15];
  const void* gp  = d_in[16];
  const void* bp  = d_in[17];
  const void* mp  = d_in[18];
  const void* vp  = d_in[19];

  char* ws = (char*)d_ws;
  bf16_t*  feat_t  = (bf16_t*)(ws);                     // 33,554,432 B
  bf16_t*  vox     = (bf16_t*)(ws + 33554432);          // 33,554,432 B
  bf16_t*  c1out   = (bf16_t*)(ws + 67108864);          // 33,554,432 B
  bf16_t*  c2out   = vox;                               // vox dead after conv1
  uint4*   sortedF = (uint4*)(ws + 100663296);          //  4,194,304 B (262144 x 16B)
  unsigned* hist   = (unsigned*)(ws + 117440512);       //  1,048,576 B
  unsigned* offs   = (unsigned*)(ws + 118489088);       //  1,048,576 B
  bf16_t*  wp1     = (bf16_t*)(ws + 119537664);         //    221,184 B
  bf16_t*  wp2     = (bf16_t*)(ws + 119758848);         //    221,184 B
  float*   P       = (float*)(ws + 119980032);          //      1,536 B
  float*   stats   = (float*)(ws + 119981568);          //        128 B
  int*     flag    = (int*)(ws + 119981696);            //        128 B
  unsigned* counter= (unsigned*)(ws + 119981824);       //        128 B
  float*   ssum    = (float*)(ws + 119981952);          //        128 B (8x4 f32)
  unsigned* smax   = (unsigned*)(ws + 119982080);       //        128 B

  hipMemsetAsync(flag, 0, 4, stream);
  hipMemsetAsync(hist, 0, 1048576, stream);
  hipMemsetAsync(counter, 0, 4, stream);
  hipMemsetAsync(ssum, 0, 256, stream);                 // ssum + smax
  detect_kernel<<<3072, 256, 0, stream>>>(coords, flag);
  prep_weights_kernel<<<432, 256, 0, stream>>>(c1w, c2w, flag, wp1, wp2);
  prep_params_kernel<<<1, 64, 0, stream>>>(c1b,g1,b1,m1,v1, c2b,g2,b2,m2,v2,
                                           mb,gp,bp,mp,vp, flag, P);
  stats_sum_kernel<<<256, 256, 0, stream>>>(coords, flag, ssum);
  stats_max_kernel<<<256, 256, 0, stream>>>(coords, flag, ssum, smax);
  stats_fin_kernel<<<1, 64, 0, stream>>>(ssum, smax, stats);
  transpose_kernel<<<4096, 256, 0, stream>>>(feat, flag, feat_t);
  hist_kernel<<<1024, 256, 0, stream>>>(coords, stats, flag, hist);
  offsets_kernel<<<1024, 256, 0, stream>>>(hist, offs, counter);
  fill_kernel<<<1024, 256, 0, stream>>>(coords, stats, flag, offs, sortedF);
  gather_kernel<<<1024, 256, 0, stream>>>(sortedF, offs, hist, feat_t, vox);
  conv3d_kernel<<<2048, 256, 0, stream>>>(vox,   wp1, P,       P + 64,  c1out);
  conv3d_kernel<<<2048, 256, 0, stream>>>(c1out, wp2, P + 128, P + 192, c2out);
  devox_kernel<<<8192, 256, 0, stream>>>(c2out, feat_t, coords, mw, stats, flag,
                                         P + 256, P + 320, d_out);
  copy_coords_kernel<<<3072, 256, 0, stream>>>(coords, d_out, flag);
}